// Round 4
// baseline (503.527 us; speedup 1.0000x reference)
//
#include <hip/hip_runtime.h>

typedef _Float16 f16;
typedef _Float16 f16x8 __attribute__((ext_vector_type(8)));
typedef _Float16 f16x4 __attribute__((ext_vector_type(4)));
typedef float    f32x4 __attribute__((ext_vector_type(4)));

#define NN 16384   // 128*128

// log-range constants: lambda(B0) in [0.33, 3.4] (hard: X>=0.5I, M0~1.5I)
#define CC 1.9f
#define WW 1.6f

struct DKA { float v[33]; };
__host__ __device__ constexpr DKA make_dk() {
  DKA d{};
  d.v[0] = 0.641853886172395f;  // ln(1.9)
  float q = 1.f;
  for (int k = 1; k < 33; ++k) { q *= (WW / CC); d.v[k] = ((k & 1) ? 1.f : -1.f) * q / (float)k; }
  return d;
}
__device__ constexpr DKA DKC = make_dk();

// ---------------- swizzled LDS index for 128x128 f16 (G4 XOR pattern) -------
__device__ __forceinline__ int swz(int r, int c) {
  return (r << 7) + ((((c >> 3) ^ (r & 7)) << 3) | (c & 7));
}

// load 128x128 fp32 (global) -> f16 swizzled LDS
__device__ __forceinline__ void load_g2l(const float* __restrict__ G, f16* buf, int t, int nt) {
  for (int ch = t; ch < 2048; ch += nt) {
    int r = ch >> 4, c8 = (ch & 15) << 3;
    const float* g = G + (r << 7) + c8;
    float4 v0 = *(const float4*)g;
    float4 v1 = *(const float4*)(g + 4);
    f16x8 h;
    h[0]=(f16)v0.x; h[1]=(f16)v0.y; h[2]=(f16)v0.z; h[3]=(f16)v0.w;
    h[4]=(f16)v1.x; h[5]=(f16)v1.y; h[6]=(f16)v1.z; h[7]=(f16)v1.w;
    *(f16x8*)(buf + swz(r, c8)) = h;
  }
}
// load 128x128 f16 (global, row-major) -> swizzled LDS
__device__ __forceinline__ void load_g2l_h(const f16* __restrict__ G, f16* buf, int t, int nt) {
  for (int ch = t; ch < 2048; ch += nt) {
    int r = ch >> 4, c8 = (ch & 15) << 3;
    *(f16x8*)(buf + swz(r, c8)) = *(const f16x8*)(G + (r << 7) + c8);
  }
}

template<int NI>
__device__ __forceinline__ void zero_acc(f32x4 (&acc)[NI][4]) {
  #pragma unroll
  for (int i = 0; i < NI; ++i)
    #pragma unroll
    for (int j = 0; j < 4; ++j) acc[i][j] = (f32x4){0.f, 0.f, 0.f, 0.f};
}

// acc += A * B̂^T, both from swizzled LDS (valid as A*B when B̂ symmetric/commuting)
template<int NI>
__device__ __forceinline__ void mm_lds(const f16* A, const f16* Bh,
                                       f32x4 (&acc)[NI][4], int w, int l) {
  const int tr0 = (w >> 1) * (16 * NI), tc0 = (w & 1) * 64;
  #pragma unroll
  for (int ks = 0; ks < 4; ++ks) {
    const int kb = ks * 32 + ((l >> 4) << 3);
    f16x8 af[NI], bf[4];
    #pragma unroll
    for (int i = 0; i < NI; ++i) af[i] = *(const f16x8*)(A  + swz(tr0 + i*16 + (l & 15), kb));
    #pragma unroll
    for (int j = 0; j < 4; ++j) bf[j] = *(const f16x8*)(Bh + swz(tc0 + j*16 + (l & 15), kb));
    #pragma unroll
    for (int i = 0; i < NI; ++i)
      #pragma unroll
      for (int j = 0; j < 4; ++j)
        acc[i][j] = __builtin_amdgcn_mfma_f32_16x16x32_f16(af[i], bf[j], acc[i][j], 0, 0, 0);
  }
}

// acc += A * B̂^T with B̂ fragments preloaded (bfr[ks*4+j])
template<int NI>
__device__ __forceinline__ void mm_pre(const f16* A, const f16x8* bfr,
                                       f32x4 (&acc)[NI][4], int w, int l) {
  const int tr0 = (w >> 1) * (16 * NI);
  #pragma unroll
  for (int ks = 0; ks < 4; ++ks) {
    const int kb = ks * 32 + ((l >> 4) << 3);
    f16x8 af[NI];
    #pragma unroll
    for (int i = 0; i < NI; ++i) af[i] = *(const f16x8*)(A + swz(tr0 + i*16 + (l & 15), kb));
    #pragma unroll
    for (int i = 0; i < NI; ++i)
      #pragma unroll
      for (int j = 0; j < 4; ++j)
        acc[i][j] = __builtin_amdgcn_mfma_f32_16x16x32_f16(af[i], bfr[ks*4+j], acc[i][j], 0, 0, 0);
  }
}

// acc += A*(B1̂^T) + A*(B2̂^T), af shared (split-B: hi+lo)
template<int NI>
__device__ __forceinline__ void mm_pre2(const f16* A, const f16x8* b1, const f16x8* b2,
                                        f32x4 (&acc)[NI][4], int w, int l) {
  const int tr0 = (w >> 1) * (16 * NI);
  #pragma unroll
  for (int ks = 0; ks < 4; ++ks) {
    const int kb = ks * 32 + ((l >> 4) << 3);
    f16x8 af[NI];
    #pragma unroll
    for (int i = 0; i < NI; ++i) af[i] = *(const f16x8*)(A + swz(tr0 + i*16 + (l & 15), kb));
    #pragma unroll
    for (int i = 0; i < NI; ++i)
      #pragma unroll
      for (int j = 0; j < 4; ++j) {
        acc[i][j] = __builtin_amdgcn_mfma_f32_16x16x32_f16(af[i], b1[ks*4+j], acc[i][j], 0, 0, 0);
        acc[i][j] = __builtin_amdgcn_mfma_f32_16x16x32_f16(af[i], b2[ks*4+j], acc[i][j], 0, 0, 0);
      }
  }
}

// preload B̂ fragments from swizzled LDS
__device__ __forceinline__ void pre_bf_lds(const f16* B, f16x8* bfr, int w, int l) {
  const int tc0 = (w & 1) * 64;
  #pragma unroll
  for (int ks = 0; ks < 4; ++ks) {
    const int kb = ks * 32 + ((l >> 4) << 3);
    #pragma unroll
    for (int j = 0; j < 4; ++j)
      bfr[ks*4+j] = *(const f16x8*)(B + swz(tc0 + j*16 + (l & 15), kb));
  }
}
// preload B̂ fragments from row-major GLOBAL f16
__device__ __forceinline__ void pre_bf_glb(const f16* __restrict__ B, f16x8* bfr, int w, int l) {
  const int tc0 = (w & 1) * 64;
  #pragma unroll
  for (int ks = 0; ks < 4; ++ks) {
    const int kb = ks * 32 + ((l >> 4) << 3);
    #pragma unroll
    for (int j = 0; j < 4; ++j)
      bfr[ks*4+j] = *(const f16x8*)(B + (tc0 + j*16 + (l & 15)) * 128 + kb);
  }
}
// preload output-position b64 chunks (transposed convention)
template<int NI>
__device__ __forceinline__ void pre_chunks(const f16* M, f16x4* Cc, int w, int l) {
  const int tr0 = (w >> 1) * (16 * NI), tc0 = (w & 1) * 64;
  #pragma unroll
  for (int i = 0; i < NI; ++i) {
    const int rowb = tr0 + i*16 + ((l >> 4) << 2);
    #pragma unroll
    for (int j = 0; j < 4; ++j)
      Cc[i*4+j] = *(const f16x4*)(M + swz(tc0 + j*16 + (l & 15), rowb));
  }
}

// transpose-packed writeback: buf[swz(col,row)] = alpha*acc + beta*[row==col]
template<int NI>
__device__ __forceinline__ void wb_t(f16* buf, const f32x4 (&acc)[NI][4], int w, int l,
                                     float alpha, float beta) {
  const int tr0 = (w >> 1) * (16 * NI), tc0 = (w & 1) * 64;
  #pragma unroll
  for (int i = 0; i < NI; ++i) {
    const int rowb = tr0 + i*16 + ((l >> 4) << 2);
    #pragma unroll
    for (int j = 0; j < 4; ++j) {
      const int colg = tc0 + j*16 + (l & 15);
      f16x4 h;
      #pragma unroll
      for (int r = 0; r < 4; ++r) {
        float v = alpha * acc[i][j][r];
        if (rowb + r == colg) v += beta;
        h[r] = (f16)v;
      }
      *(f16x4*)(buf + swz(colg, rowb)) = h;
    }
  }
}

// transpose-packed split writeback (hi+lo f16)
template<int NI>
__device__ __forceinline__ void wb_t_split(f16* bh, f16* bl, const f32x4 (&acc)[NI][4],
                                           int w, int l) {
  const int tr0 = (w >> 1) * (16 * NI), tc0 = (w & 1) * 64;
  #pragma unroll
  for (int i = 0; i < NI; ++i) {
    const int rowb = tr0 + i*16 + ((l >> 4) << 2);
    #pragma unroll
    for (int j = 0; j < 4; ++j) {
      const int colg = tc0 + j*16 + (l & 15);
      f16x4 hh, hl;
      #pragma unroll
      for (int r = 0; r < 4; ++r) {
        float v = acc[i][j][r];
        f16 hi = (f16)v;
        hh[r] = hi; hl[r] = (f16)(v - (float)hi);
      }
      *(f16x4*)(bh + swz(colg, rowb)) = hh;
      *(f16x4*)(bl + swz(colg, rowb)) = hl;
    }
  }
}

// transpose writeback: v = acc + d0*I + d1*Uc + d2*U2c + d3*U3c (chunks in regs)
template<int NI>
__device__ __forceinline__ void wb_t_combo4(f16* buf, const f32x4 (&acc)[NI][4],
                                            const f16x4* Uc, const f16x4* U2c, const f16x4* U3c,
                                            int w, int l, float d0, float d1, float d2, float d3) {
  const int tr0 = (w >> 1) * (16 * NI), tc0 = (w & 1) * 64;
  #pragma unroll
  for (int i = 0; i < NI; ++i) {
    const int rowb = tr0 + i*16 + ((l >> 4) << 2);
    #pragma unroll
    for (int j = 0; j < 4; ++j) {
      const int colg = tc0 + j*16 + (l & 15);
      f16x4 h;
      #pragma unroll
      for (int r = 0; r < 4; ++r) {
        float v = acc[i][j][r] + d1 * (float)Uc[i*4+j][r] + d2 * (float)U2c[i*4+j][r]
                               + d3 * (float)U3c[i*4+j][r];
        if (rowb + r == colg) v += d0;
        h[r] = (f16)v;
      }
      *(f16x4*)(buf + swz(colg, rowb)) = h;
    }
  }
}

// transpose writeback with combo read from LDS buffers C1,C2
template<int NI>
__device__ __forceinline__ void wb_t_gc(f16* buf, const f32x4 (&acc)[NI][4],
                                        const f16* C1, const f16* C2,
                                        int w, int l, float d0, float d1, float d2) {
  const int tr0 = (w >> 1) * (16 * NI), tc0 = (w & 1) * 64;
  #pragma unroll
  for (int i = 0; i < NI; ++i) {
    const int rowb = tr0 + i*16 + ((l >> 4) << 2);
    #pragma unroll
    for (int j = 0; j < 4; ++j) {
      const int colg = tc0 + j*16 + (l & 15);
      f16x4 c1 = *(const f16x4*)(C1 + swz(colg, rowb));
      f16x4 c2 = *(const f16x4*)(C2 + swz(colg, rowb));
      f16x4 h;
      #pragma unroll
      for (int r = 0; r < 4; ++r) {
        float v = acc[i][j][r] + d1 * (float)c1[r] + d2 * (float)c2[r];
        if (rowb + r == colg) v += d0;
        h[r] = (f16)v;
      }
      *(f16x4*)(buf + swz(colg, rowb)) = h;
    }
  }
}

// async stage: raw fp32 X (64KB) -> LDS buffers b1(32KB)+b3(32KB), linear
__device__ __forceinline__ void stage_issue(const float* __restrict__ Xn,
                                            f16* b1, f16* b3, int t) {
  const int w = t >> 6, l = t & 63;
  #pragma unroll
  for (int q = 0; q < 8; ++q) {
    const int cb = (w * 8 + q) * 64;            // base 16B-chunk (wave-uniform)
    const float* src = Xn + (size_t)(cb + l) * 4;
    f16* dstbase = (cb < 2048) ? (f16*)((char*)b1 + (size_t)cb * 16)
                               : (f16*)((char*)b3 + (size_t)(cb - 2048) * 16);
    __builtin_amdgcn_global_load_lds(
        (const __attribute__((address_space(1))) unsigned int*)src,
        (__attribute__((address_space(3))) unsigned int*)dstbase, 16, 0, 0);
  }
}
// staged raw fp32 (b1,b3) -> swizzled f16 dst
__device__ __forceinline__ void convert_staged(const f16* b1, const f16* b3, f16* dst, int t) {
  for (int g = t; g < 2048; g += 512) {
    int r = g >> 4, c8 = (g & 15) << 3;
    int f0 = g * 8;
    const float* src = (f0 < 8192) ? (const float*)b1 + f0 : (const float*)b3 + (f0 - 8192);
    float4 v0 = *(const float4*)src;
    float4 v1 = *(const float4*)(src + 4);
    f16x8 h;
    h[0]=(f16)v0.x; h[1]=(f16)v0.y; h[2]=(f16)v0.z; h[3]=(f16)v0.w;
    h[4]=(f16)v1.x; h[5]=(f16)v1.y; h[6]=(f16)v1.z; h[7]=(f16)v1.w;
    *(f16x8*)(dst + swz(r, c8)) = h;
  }
}

// =================== phase A: batch mean (float4) ===================
__global__ void k_mean_part(const float* __restrict__ X, float* __restrict__ part, int nper) {
  int e4 = blockIdx.x * 256 + threadIdx.x;     // grid (16,16): 4096 float4/matrix
  int bc = blockIdx.y;
  const float4* p = (const float4*)X + (size_t)bc * nper * 4096 + e4;
  float4 s = {0.f, 0.f, 0.f, 0.f};
  for (int b = 0; b < nper; ++b) {
    float4 v = p[(size_t)b * 4096];
    s.x += v.x; s.y += v.y; s.z += v.z; s.w += v.w;
  }
  ((float4*)part)[(size_t)bc * 4096 + e4] = s;
}
__global__ void k_mean_fin(const float* __restrict__ part, float* __restrict__ M0, float scale) {
  int e4 = blockIdx.x * 256 + threadIdx.x;     // 16 blocks
  float4 s = {0.f, 0.f, 0.f, 0.f};
  for (int c = 0; c < 16; ++c) {
    float4 v = ((const float4*)part)[(size_t)c * 4096 + e4];
    s.x += v.x; s.y += v.y; s.z += v.z; s.w += v.w;
  }
  s.x *= scale; s.y *= scale; s.z *= scale; s.w *= scale;
  ((float4*)M0)[e4] = s;
}

// =================== kB: Cp=M0^{-1/2} (split), R=M0^{1/2} (split) ===========
// NOTE: launch_bounds min-waves/EU = 1.  LDS (128KB) already limits to
// 1 block/CU; asking for more only caps VGPRs (r3: cap 128 -> spill -> 430MB
// of scratch HBM traffic, the round-3 regression).
__global__ __launch_bounds__(512, 1) void kB(
    const float* __restrict__ M0,
    f16* __restrict__ Cph, f16* __restrict__ Cpl,
    f16* __restrict__ Rh,  f16* __restrict__ Rl) {
  __shared__ __align__(16) f16 A1[NN], A2[NN], A3[NN], A4[NN];
  __shared__ float red[128];
  __shared__ float sS;
  const int t = threadIdx.x, w = t >> 6, l = t & 63;
  if (t < 128) red[t] = M0[t * 129];
  __syncthreads();
  for (int s = 64; s > 0; s >>= 1) { if (t < s) red[t] += red[t + s]; __syncthreads(); }
  if (t == 0) sS = red[0] / 128.f;
  __syncthreads();
  const float s = sS, inv = 1.f / s;
  for (int e = t; e < NN; e += 512) {
    int r = e >> 7, c = e & 127;
    A1[swz(r, c)] = (f16)(M0[e] * inv - (r == c ? 1.f : 0.f));
  }
  __syncthreads();
  f32x4 acc[2][4];
  zero_acc<2>(acc); mm_lds<2>(A1, A1, acc, w, l); wb_t<2>(A2, acc, w, l, 1.f, 0.f); __syncthreads();
  zero_acc<2>(acc); mm_lds<2>(A2, A1, acc, w, l); wb_t<2>(A3, acc, w, l, 1.f, 0.f); __syncthreads();
  zero_acc<2>(acc); mm_lds<2>(A2, A2, acc, w, l); wb_t<2>(A4, acc, w, l, 1.f, 0.f); __syncthreads();
  const float rs = sqrtf(s), irs = 1.f / rs;
  for (int e = t; e < NN; e += 512) {
    int r = e >> 7, c = e & 127; int ix = swz(r, c);
    float a1 = (float)A1[ix], a2 = (float)A2[ix], a3 = (float)A3[ix], a4 = (float)A4[ix];
    float d = (r == c) ? 1.f : 0.f;
    float cp = (d - 0.5f*a1 + 0.375f*a2 - 0.3125f*a3 + 0.2734375f*a4) * irs;
    float rr = (d + 0.5f*a1 - 0.125f*a2 + 0.0625f*a3 - 0.0390625f*a4) * rs;
    f16 ch = (f16)cp; Cph[e] = ch; Cpl[e] = (f16)(cp - (float)ch);
    f16 rh = (f16)rr; Rh[e]  = rh; Rl[e]  = (f16)(rr - (float)rh);
  }
}

// ===== phase C: sum of matrix logs (deg-31 poly, PS stride U^4, 12 mm/matrix)
__global__ __launch_bounds__(512, 1) void k_batch_log(
    const float* __restrict__ X, const f16* __restrict__ Cph, const f16* __restrict__ Cpl,
    float* __restrict__ Ppart, int per_blk) {
  __shared__ __align__(16) f16 S0[NN], S1[NN], S2[NN], S3[NN];   // 128 KB
  const int t = threadIdx.x, w = t >> 6, l = t & 63;
  f32x4 lsum[2][4]; zero_acc<2>(lsum);
  f32x4 acc[2][4];
  for (int m = 0; m < per_blk; ++m) {
    const size_t b = (size_t)blockIdx.x * per_blk + m;
    if (m == 0) {
      load_g2l(X + b * NN, S0, t, 512);
    } else {
      asm volatile("s_waitcnt vmcnt(0)" ::: "memory");
      __syncthreads();                      // staged X visible everywhere; S0 free
      convert_staged(S1, S3, S0, t);
    }
    {
      f16x8 bch[16], bcl[16];
      pre_bf_glb(Cph, bch, w, l);
      pre_bf_glb(Cpl, bcl, w, l);
      __syncthreads();                      // X in S0 ready
      // pass1: acc = X*Cp^T -> store^T = Cp*X = T -> S1
      zero_acc<2>(acc); mm_pre2<2>(S0, bch, bcl, acc, w, l);
      wb_t<2>(S1, acc, w, l, 1.f, 0.f); __syncthreads();
      // pass2: acc = T*Cp -> U = (B0 - c I)/w -> S0
      zero_acc<2>(acc); mm_pre2<2>(S1, bch, bcl, acc, w, l);
      wb_t<2>(S0, acc, w, l, 1.f / WW, -CC / WW); __syncthreads();
    }
    // U2 -> S2, U3 -> S3, U4 -> S1
    zero_acc<2>(acc); mm_lds<2>(S0, S0, acc, w, l); wb_t<2>(S2, acc, w, l, 1.f, 0.f); __syncthreads();
    zero_acc<2>(acc); mm_lds<2>(S2, S0, acc, w, l); wb_t<2>(S3, acc, w, l, 1.f, 0.f); __syncthreads();
    zero_acc<2>(acc); mm_lds<2>(S2, S2, acc, w, l); wb_t<2>(S1, acc, w, l, 1.f, 0.f); __syncthreads();
    // register preloads: U4 fragments; U,U2,U3 combo chunks
    f16x8 bfr[16]; f16x4 Uc[8], U2c[8], U3c[8];
    pre_bf_lds(S1, bfr, w, l);
    pre_chunks<2>(S0, Uc, w, l);
    pre_chunks<2>(S2, U2c, w, l);
    pre_chunks<2>(S3, U3c, w, l);
    __syncthreads();
    // H-init: g7 = d28 I + d29 U + d30 U2 + d31 U3 -> S0 (in place over U)
    for (int g = t; g < 2048; g += 512) {
      int e0 = g * 8;
      f16x8 u  = *(const f16x8*)(S0 + e0);
      f16x8 u2 = *(const f16x8*)(S2 + e0);
      f16x8 u3 = *(const f16x8*)(S3 + e0);
      int r = e0 >> 7;
      int c0 = ((((e0 >> 3) & 15) ^ (r & 7)) << 3);
      f16x8 h;
      #pragma unroll
      for (int k = 0; k < 8; ++k) {
        float v = DKC.v[29] * (float)u[k] + DKC.v[30] * (float)u2[k] + DKC.v[31] * (float)u3[k];
        if (r == c0 + k) v += DKC.v[28];
        h[k] = (f16)v;
      }
      *(f16x8*)(S0 + e0) = h;
    }
    __syncthreads();
    // prefetch next X into dead S1/S3 (raw fp32) while Horner runs
    if (m + 1 < per_blk) stage_issue(X + (b + 1) * NN, S1, S3, t);
    // Horner j=6..1 ping-pong S0 <-> S2 (1 barrier/pass)
    f16* pc = S0; f16* pn = S2;
    #pragma unroll
    for (int jj = 6; jj >= 1; --jj) {
      zero_acc<2>(acc);
      mm_pre<2>(pc, bfr, acc, w, l);
      wb_t_combo4<2>(pn, acc, Uc, U2c, U3c, w, l,
                     DKC.v[4*jj], DKC.v[4*jj+1], DKC.v[4*jj+2], DKC.v[4*jj+3]);
      __syncthreads();
      f16* tmp = pc; pc = pn; pn = tmp;
    }
    // final block j=0: accumulate into lsum, no store
    zero_acc<2>(acc);
    mm_pre<2>(pc, bfr, acc, w, l);
    {
      const int tr0 = (w >> 1) * 32, tc0 = (w & 1) * 64;
      #pragma unroll
      for (int i = 0; i < 2; ++i) {
        const int rowb = tr0 + i*16 + ((l >> 4) << 2);
        #pragma unroll
        for (int j = 0; j < 4; ++j) {
          const int colg = tc0 + j*16 + (l & 15);
          #pragma unroll
          for (int r = 0; r < 4; ++r) {
            float v = acc[i][j][r] + DKC.v[1] * (float)Uc[i*4+j][r]
                    + DKC.v[2] * (float)U2c[i*4+j][r] + DKC.v[3] * (float)U3c[i*4+j][r];
            if (rowb + r == colg) v += DKC.v[0];
            lsum[i][j][r] += v;
          }
        }
      }
    }
    __syncthreads();
  }
  // store partials (sum of logs is symmetric -> transposed float4 store is exact)
  float* pp = Ppart + (size_t)blockIdx.x * NN;
  const int tr0 = (w >> 1) * 32, tc0 = (w & 1) * 64;
  #pragma unroll
  for (int i = 0; i < 2; ++i) {
    const int rowb = tr0 + i*16 + ((l >> 4) << 2);
    #pragma unroll
    for (int j = 0; j < 4; ++j) {
      const int colg = tc0 + j*16 + (l & 15);
      *(f32x4*)(pp + colg * 128 + rowb) = lsum[i][j];
    }
  }
}

__global__ void k_reduceP(const float* __restrict__ Pp, float* __restrict__ P, float invBn) {
  int e4 = blockIdx.x * 256 + threadIdx.x;    // 16 blocks
  f32x4 s = {0.f, 0.f, 0.f, 0.f};
  for (int b = 0; b < 256; ++b) {
    f32x4 v = ((const f32x4*)Pp)[(size_t)b * 4096 + e4];
    s = s + v;
  }
  ((f32x4*)P)[e4] = s * invBn;
}

// ========= kD: E=exp(P) (deg-8), BM=R E R, S=BM^{-1/2}, T=mean^{1/2}, G=T*S ==
__global__ __launch_bounds__(512, 1) void kD(
    const float* __restrict__ P, const float* __restrict__ mean,
    const f16* __restrict__ Rh, const f16* __restrict__ Rl,
    f16* __restrict__ Gh, f16* __restrict__ Gl) {
  __shared__ __align__(16) f16 B1[NN], B2[NN], B3[NN], B4[NN];
  __shared__ float red[128];
  __shared__ float sv;
  const int t = threadIdx.x, w = t >> 6, l = t & 63;
  f32x4 acc[2][4];
  // mu = tr(P)/128
  if (t < 128) red[t] = P[t * 129];
  __syncthreads();
  for (int s = 64; s > 0; s >>= 1) { if (t < s) red[t] += red[t + s]; __syncthreads(); }
  if (t == 0) sv = red[0] / 128.f;
  __syncthreads();
  const float mu = sv;
  // D -> B1
  for (int e = t; e < NN; e += 512) {
    int r = e >> 7, c = e & 127;
    B1[swz(r, c)] = (f16)(P[e] - (r == c ? mu : 0.f));
  }
  __syncthreads();
  // D2 -> B2, D3 -> B3
  zero_acc<2>(acc); mm_lds<2>(B1, B1, acc, w, l); wb_t<2>(B2, acc, w, l, 1.f, 0.f); __syncthreads();
  zero_acc<2>(acc); mm_lds<2>(B2, B1, acc, w, l); wb_t<2>(B3, acc, w, l, 1.f, 0.f); __syncthreads();
  // T = g2 = I/720 + D/5040 + D2/40320 -> B4
  for (int g = t; g < 2048; g += 512) {
    int e0 = g * 8;
    f16x8 d1 = *(const f16x8*)(B1 + e0);
    f16x8 d2 = *(const f16x8*)(B2 + e0);
    int r = e0 >> 7;
    int c0 = ((((e0 >> 3) & 15) ^ (r & 7)) << 3);
    f16x8 h;
    #pragma unroll
    for (int k = 0; k < 8; ++k) {
      float v = (1.f/5040.f) * (float)d1[k] + (1.f/40320.f) * (float)d2[k];
      if (r == c0 + k) v += (1.f/720.f);
      h[k] = (f16)v;
    }
    *(f16x8*)(B4 + e0) = h;
  }
  __syncthreads();
  // T <- D3*T + g1 (g1 = I/6 + D/24 + D2/120), in place B4 (needs mid barrier)
  zero_acc<2>(acc); mm_lds<2>(B3, B4, acc, w, l); __syncthreads();
  wb_t_gc<2>(B4, acc, B1, B2, w, l, 1.f/6.f, 1.f/24.f, 1.f/120.f);
  __syncthreads();
  // E = e^mu * (D3*T + I + D + D2/2): split -> Eh:B2, El:B3
  zero_acc<2>(acc); mm_lds<2>(B3, B4, acc, w, l); __syncthreads();
  {
    const float emu = expf(mu);
    const int tr0 = (w >> 1) * 32, tc0 = (w & 1) * 64;
    #pragma unroll
    for (int i = 0; i < 2; ++i) {
      const int rowb = tr0 + i*16 + ((l >> 4) << 2);
      #pragma unroll
      for (int j = 0; j < 4; ++j) {
        const int colg = tc0 + j*16 + (l & 15);
        f16x4 dc  = *(const f16x4*)(B1 + swz(colg, rowb));
        f16x4 d2c = *(const f16x4*)(B2 + swz(colg, rowb));
        f16x4 hh, hl;
        #pragma unroll
        for (int r = 0; r < 4; ++r) {
          float v = acc[i][j][r] + (float)dc[r] + 0.5f * (float)d2c[r];
          if (rowb + r == colg) v += 1.f;
          v *= emu;
          f16 hi = (f16)v; hh[r] = hi; hl[r] = (f16)(v - (float)hi);
        }
        *(f16x4*)(B2 + swz(colg, rowb)) = hh;
        *(f16x4*)(B3 + swz(colg, rowb)) = hl;
      }
    }
  }
  __syncthreads();
  // R into LDS
  load_g2l_h(Rh, B1, t, 512);
  load_g2l_h(Rl, B4, t, 512);
  __syncthreads();
  // T1 = E*R (buffer holds (E*R)^T): split -> B2,B3
  zero_acc<2>(acc);
  mm_lds<2>(B2, B1, acc, w, l);   // Eh*Rh
  mm_lds<2>(B2, B4, acc, w, l);   // Eh*Rl
  mm_lds<2>(B3, B1, acc, w, l);   // El*Rh
  __syncthreads();
  wb_t_split<2>(B2, B3, acc, w, l);
  __syncthreads();
  // BM = R*T1: A=R, B̂buf=(E*R)^T -> split B2,B3 (BM symmetric)
  zero_acc<2>(acc);
  mm_lds<2>(B1, B2, acc, w, l);   // Rh*T1h
  mm_lds<2>(B1, B3, acc, w, l);   // Rh*T1l
  mm_lds<2>(B4, B2, acc, w, l);   // Rl*T1h
  __syncthreads();
  wb_t_split<2>(B2, B3, acc, w, l);
  __syncthreads();
  // s2 = tr(BM)/128
  if (t < 128) red[t] = (float)B2[swz(t, t)] + (float)B3[swz(t, t)];
  __syncthreads();
  for (int s = 64; s > 0; s >>= 1) { if (t < s) red[t] += red[t + s]; __syncthreads(); }
  if (t == 0) sv = red[0] / 128.f;
  __syncthreads();
  const float s2 = sv, inv2 = 1.f / s2;
  // F = BM/s2 - I -> B1
  for (int e = t; e < NN; e += 512) {
    int r = e >> 7, c = e & 127; int ix = swz(r, c);
    B1[ix] = (f16)(((float)B2[ix] + (float)B3[ix]) * inv2 - (r == c ? 1.f : 0.f));
  }
  __syncthreads();
  // F2 -> B4, F3 -> B2, F4 -> B3
  zero_acc<2>(acc); mm_lds<2>(B1, B1, acc, w, l); wb_t<2>(B4, acc, w, l, 1.f, 0.f); __syncthreads();
  zero_acc<2>(acc); mm_lds<2>(B4, B1, acc, w, l); wb_t<2>(B2, acc, w, l, 1.f, 0.f); __syncthreads();
  zero_acc<2>(acc); mm_lds<2>(B4, B4, acc, w, l); wb_t<2>(B3, acc, w, l, 1.f, 0.f); __syncthreads();
  // S = (I - F/2 + 3F2/8 - 5F3/16 + 35F4/128)/sqrt(s2): split -> Sh:B1, Sl:B4
  {
    const float is2 = 1.f / sqrtf(s2);
    for (int e = t; e < NN; e += 512) {
      int r = e >> 7, c = e & 127; int ix = swz(r, c);
      float f1 = (float)B1[ix], f2 = (float)B4[ix], f3 = (float)B2[ix], f4 = (float)B3[ix];
      float d = (r == c) ? 1.f : 0.f;
      float vv = (d - 0.5f*f1 + 0.375f*f2 - 0.3125f*f3 + 0.2734375f*f4) * is2;
      f16 hi = (f16)vv;
      B1[ix] = hi; B4[ix] = (f16)(vv - (float)hi);
    }
  }
  __syncthreads();
  // T_sqrt = mean^{1/2}: s3 = tr(mean)/128, M -> B2, M2 -> B3
  if (t < 128) red[t] = mean[t * 129];
  __syncthreads();
  for (int s = 64; s > 0; s >>= 1) { if (t < s) red[t] += red[t + s]; __syncthreads(); }
  if (t == 0) sv = red[0] / 128.f;
  __syncthreads();
  const float s3 = sv, inv3 = 1.f / s3;
  for (int e = t; e < NN; e += 512) {
    int r = e >> 7, c = e & 127;
    B2[swz(r, c)] = (f16)(mean[e] * inv3 - (r == c ? 1.f : 0.f));
  }
  __syncthreads();
  zero_acc<2>(acc); mm_lds<2>(B2, B2, acc, w, l); __syncthreads();
  wb_t<2>(B3, acc, w, l, 1.f, 0.f); __syncthreads();
  {
    const float rs3 = sqrtf(s3);
    for (int e = t; e < NN; e += 512) {
      int r = e >> 7, c = e & 127; int ix = swz(r, c);
      float m1 = (float)B2[ix], m2 = (float)B3[ix];
      float d = (r == c) ? 1.f : 0.f;
      float vv = (d + 0.5f*m1 - 0.125f*m2) * rs3;
      f16 hi = (f16)vv;
      B2[ix] = hi; B3[ix] = (f16)(vv - (float)hi);
    }
  }
  __syncthreads();
  // G = T*S: acc = S*T (A=S: B1,B4; B̂=T: B2,B3), store transposed -> G (global)
  zero_acc<2>(acc);
  mm_lds<2>(B1, B2, acc, w, l);   // Sh*Th
  mm_lds<2>(B1, B3, acc, w, l);   // Sh*Tl
  mm_lds<2>(B4, B2, acc, w, l);   // Sl*Th
  {
    const int tr0 = (w >> 1) * 32, tc0 = (w & 1) * 64;
    #pragma unroll
    for (int i = 0; i < 2; ++i) {
      const int rowb = tr0 + i*16 + ((l >> 4) << 2);
      #pragma unroll
      for (int j = 0; j < 4; ++j) {
        const int colg = tc0 + j*16 + (l & 15);
        f16x4 hh, hl;
        #pragma unroll
        for (int r = 0; r < 4; ++r) {
          float v = acc[i][j][r];
          f16 hi = (f16)v; hh[r] = hi; hl[r] = (f16)(v - (float)hi);
        }
        *(f16x4*)(Gh + colg * 128 + rowb) = hh;
        *(f16x4*)(Gl + colg * 128 + rowb) = hl;
      }
    }
  }
}

// =================== phase E: Xn = G * X * G^T ===================
__global__ __launch_bounds__(256, 2) void k_apply(
    const float* __restrict__ X, const f16* __restrict__ Gh, const f16* __restrict__ Gl,
    float* __restrict__ Out, int per_blk) {
  __shared__ __align__(16) f16 SX[NN], ST[NN];
  const int t = threadIdx.x, w = t >> 6, l = t & 63;
  f16x8 bgh[16], bgl[16];
  pre_bf_glb(Gh, bgh, w, l);
  pre_bf_glb(Gl, bgl, w, l);
  f32x4 acc[4][4];
  for (int m = 0; m < per_blk; ++m) {
    const size_t b = (size_t)blockIdx.x * per_blk + m;
    load_g2l(X + b * NN, SX, t, 256);
    __syncthreads();
    // acc = X*G^T -> store^T = G*X = T
    zero_acc<4>(acc); mm_pre2<4>(SX, bgh, bgl, acc, w, l); __syncthreads();
    wb_t<4>(ST, acc, w, l, 1.f, 0.f); __syncthreads();
    // acc = T*G^T = G X G^T -> global (symmetric: transposed float4 store exact)
    zero_acc<4>(acc); mm_pre2<4>(ST, bgh, bgl, acc, w, l);
    float* O = Out + b * NN;
    const int tr0 = (w >> 1) * 64, tc0 = (w & 1) * 64;
    #pragma unroll
    for (int i = 0; i < 4; ++i) {
      const int rowb = tr0 + i*16 + ((l >> 4) << 2);
      #pragma unroll
      for (int j = 0; j < 4; ++j) {
        const int colg = tc0 + j*16 + (l & 15);
        *(f32x4*)(O + colg * 128 + rowb) = acc[i][j];
      }
    }
    __syncthreads();
  }
}

// =================== host ===================
extern "C" void kernel_launch(void* const* d_in, const int* in_sizes, int n_in,
                              void* d_out, int out_size, void* d_ws, size_t ws_size,
                              hipStream_t stream) {
  const float* X    = (const float*)d_in[0];
  const float* mean = (const float*)d_in[1];
  // d_in[2] (running_mean) mathematically unused: eta=1.0 makes
  // rm_sqrt @ powm(rm_invsqrt@BM@rm_invsqrt, 1) @ rm_sqrt == BM for ANY SPD rm.
  const int Bn = in_sizes[0] / NN;       // 2048

  float* wsf = (float*)d_ws;
  float* M0 = wsf;
  float* P  = wsf + NN;
  f16* hbase = (f16*)(wsf + 2 * (size_t)NN);
  f16 *Cph = hbase,            *Cpl = hbase + NN;
  f16 *Rh  = hbase + 2 * NN,   *Rl  = hbase + 3 * NN;
  f16 *Gh  = hbase + 4 * NN,   *Gl  = hbase + 5 * NN;
  float* Ppart = wsf + 5 * (size_t)NN;   // 256 slots (16 MB); also mean partials

  k_mean_part<<<dim3(16, 16), 256, 0, stream>>>(X, Ppart, Bn / 16);
  k_mean_fin<<<16, 256, 0, stream>>>(Ppart, M0, 1.f / (float)Bn);
  kB<<<1, 512, 0, stream>>>(M0, Cph, Cpl, Rh, Rl);
  k_batch_log<<<256, 512, 0, stream>>>(X, Cph, Cpl, Ppart, Bn / 256);
  k_reduceP<<<16, 256, 0, stream>>>(Ppart, P, 1.f / (float)Bn);
  kD<<<1, 512, 0, stream>>>(P, mean, Rh, Rl, Gh, Gl);
  k_apply<<<512, 256, 0, stream>>>(X, Gh, Gl, (float*)d_out, Bn / 512);
}

// Round 5
// 498.634 us; speedup vs baseline: 1.0098x; 1.0098x over previous
//
#include <hip/hip_runtime.h>

typedef _Float16 f16;
typedef _Float16 f16x8 __attribute__((ext_vector_type(8)));
typedef _Float16 f16x4 __attribute__((ext_vector_type(4)));
typedef float    f32x4 __attribute__((ext_vector_type(4)));

#define NN 16384   // 128*128

// log-range constants: lambda(B0) in [0.33, 3.4] (hard: X>=0.5I, M0~1.5I)
#define CC 1.9f
#define WW 1.6f

struct DKA { float v[33]; };
__host__ __device__ constexpr DKA make_dk() {
  DKA d{};
  d.v[0] = 0.641853886172395f;  // ln(1.9)
  float q = 1.f;
  for (int k = 1; k < 33; ++k) { q *= (WW / CC); d.v[k] = ((k & 1) ? 1.f : -1.f) * q / (float)k; }
  return d;
}
__device__ constexpr DKA DKC = make_dk();

// ---------------- swizzled LDS index for 128x128 f16 (G4 XOR pattern) -------
__device__ __forceinline__ int swz(int r, int c) {
  return (r << 7) + ((((c >> 3) ^ (r & 7)) << 3) | (c & 7));
}

// load 128x128 fp32 (global) -> f16 swizzled LDS
__device__ __forceinline__ void load_g2l(const float* __restrict__ G, f16* buf, int t, int nt) {
  for (int ch = t; ch < 2048; ch += nt) {
    int r = ch >> 4, c8 = (ch & 15) << 3;
    const float* g = G + (r << 7) + c8;
    float4 v0 = *(const float4*)g;
    float4 v1 = *(const float4*)(g + 4);
    f16x8 h;
    h[0]=(f16)v0.x; h[1]=(f16)v0.y; h[2]=(f16)v0.z; h[3]=(f16)v0.w;
    h[4]=(f16)v1.x; h[5]=(f16)v1.y; h[6]=(f16)v1.z; h[7]=(f16)v1.w;
    *(f16x8*)(buf + swz(r, c8)) = h;
  }
}
// load 128x128 f16 (global, row-major) -> swizzled LDS
__device__ __forceinline__ void load_g2l_h(const f16* __restrict__ G, f16* buf, int t, int nt) {
  for (int ch = t; ch < 2048; ch += nt) {
    int r = ch >> 4, c8 = (ch & 15) << 3;
    *(f16x8*)(buf + swz(r, c8)) = *(const f16x8*)(G + (r << 7) + c8);
  }
}

template<int NI>
__device__ __forceinline__ void zero_acc(f32x4 (&acc)[NI][4]) {
  #pragma unroll
  for (int i = 0; i < NI; ++i)
    #pragma unroll
    for (int j = 0; j < 4; ++j) acc[i][j] = (f32x4){0.f, 0.f, 0.f, 0.f};
}

// acc += A * B̂^T, both from swizzled LDS (valid as A*B when B̂ symmetric/commuting)
template<int NI>
__device__ __forceinline__ void mm_lds(const f16* A, const f16* Bh,
                                       f32x4 (&acc)[NI][4], int w, int l) {
  const int tr0 = (w >> 1) * (16 * NI), tc0 = (w & 1) * 64;
  #pragma unroll
  for (int ks = 0; ks < 4; ++ks) {
    const int kb = ks * 32 + ((l >> 4) << 3);
    f16x8 af[NI], bf[4];
    #pragma unroll
    for (int i = 0; i < NI; ++i) af[i] = *(const f16x8*)(A  + swz(tr0 + i*16 + (l & 15), kb));
    #pragma unroll
    for (int j = 0; j < 4; ++j) bf[j] = *(const f16x8*)(Bh + swz(tc0 + j*16 + (l & 15), kb));
    #pragma unroll
    for (int i = 0; i < NI; ++i)
      #pragma unroll
      for (int j = 0; j < 4; ++j)
        acc[i][j] = __builtin_amdgcn_mfma_f32_16x16x32_f16(af[i], bf[j], acc[i][j], 0, 0, 0);
  }
}

// acc += A * B̂^T with B̂ fragments preloaded (bfr[ks*4+j])
template<int NI>
__device__ __forceinline__ void mm_pre(const f16* A, const f16x8* bfr,
                                       f32x4 (&acc)[NI][4], int w, int l) {
  const int tr0 = (w >> 1) * (16 * NI);
  #pragma unroll
  for (int ks = 0; ks < 4; ++ks) {
    const int kb = ks * 32 + ((l >> 4) << 3);
    f16x8 af[NI];
    #pragma unroll
    for (int i = 0; i < NI; ++i) af[i] = *(const f16x8*)(A + swz(tr0 + i*16 + (l & 15), kb));
    #pragma unroll
    for (int i = 0; i < NI; ++i)
      #pragma unroll
      for (int j = 0; j < 4; ++j)
        acc[i][j] = __builtin_amdgcn_mfma_f32_16x16x32_f16(af[i], bfr[ks*4+j], acc[i][j], 0, 0, 0);
  }
}

// acc += A*(B1̂^T) + A*(B2̂^T), af shared (split-B: hi+lo)
template<int NI>
__device__ __forceinline__ void mm_pre2(const f16* A, const f16x8* b1, const f16x8* b2,
                                        f32x4 (&acc)[NI][4], int w, int l) {
  const int tr0 = (w >> 1) * (16 * NI);
  #pragma unroll
  for (int ks = 0; ks < 4; ++ks) {
    const int kb = ks * 32 + ((l >> 4) << 3);
    f16x8 af[NI];
    #pragma unroll
    for (int i = 0; i < NI; ++i) af[i] = *(const f16x8*)(A + swz(tr0 + i*16 + (l & 15), kb));
    #pragma unroll
    for (int i = 0; i < NI; ++i)
      #pragma unroll
      for (int j = 0; j < 4; ++j) {
        acc[i][j] = __builtin_amdgcn_mfma_f32_16x16x32_f16(af[i], b1[ks*4+j], acc[i][j], 0, 0, 0);
        acc[i][j] = __builtin_amdgcn_mfma_f32_16x16x32_f16(af[i], b2[ks*4+j], acc[i][j], 0, 0, 0);
      }
  }
}

// preload B̂ fragments from swizzled LDS
__device__ __forceinline__ void pre_bf_lds(const f16* B, f16x8* bfr, int w, int l) {
  const int tc0 = (w & 1) * 64;
  #pragma unroll
  for (int ks = 0; ks < 4; ++ks) {
    const int kb = ks * 32 + ((l >> 4) << 3);
    #pragma unroll
    for (int j = 0; j < 4; ++j)
      bfr[ks*4+j] = *(const f16x8*)(B + swz(tc0 + j*16 + (l & 15), kb));
  }
}
// preload B̂ fragments from row-major GLOBAL f16
__device__ __forceinline__ void pre_bf_glb(const f16* __restrict__ B, f16x8* bfr, int w, int l) {
  const int tc0 = (w & 1) * 64;
  #pragma unroll
  for (int ks = 0; ks < 4; ++ks) {
    const int kb = ks * 32 + ((l >> 4) << 3);
    #pragma unroll
    for (int j = 0; j < 4; ++j)
      bfr[ks*4+j] = *(const f16x8*)(B + (tc0 + j*16 + (l & 15)) * 128 + kb);
  }
}
// preload output-position b64 chunks (transposed convention)
template<int NI>
__device__ __forceinline__ void pre_chunks(const f16* M, f16x4* Cc, int w, int l) {
  const int tr0 = (w >> 1) * (16 * NI), tc0 = (w & 1) * 64;
  #pragma unroll
  for (int i = 0; i < NI; ++i) {
    const int rowb = tr0 + i*16 + ((l >> 4) << 2);
    #pragma unroll
    for (int j = 0; j < 4; ++j)
      Cc[i*4+j] = *(const f16x4*)(M + swz(tc0 + j*16 + (l & 15), rowb));
  }
}

// transpose-packed writeback: buf[swz(col,row)] = alpha*acc + beta*[row==col]
template<int NI>
__device__ __forceinline__ void wb_t(f16* buf, const f32x4 (&acc)[NI][4], int w, int l,
                                     float alpha, float beta) {
  const int tr0 = (w >> 1) * (16 * NI), tc0 = (w & 1) * 64;
  #pragma unroll
  for (int i = 0; i < NI; ++i) {
    const int rowb = tr0 + i*16 + ((l >> 4) << 2);
    #pragma unroll
    for (int j = 0; j < 4; ++j) {
      const int colg = tc0 + j*16 + (l & 15);
      f16x4 h;
      #pragma unroll
      for (int r = 0; r < 4; ++r) {
        float v = alpha * acc[i][j][r];
        if (rowb + r == colg) v += beta;
        h[r] = (f16)v;
      }
      *(f16x4*)(buf + swz(colg, rowb)) = h;
    }
  }
}

// transpose-packed split writeback (hi+lo f16)
template<int NI>
__device__ __forceinline__ void wb_t_split(f16* bh, f16* bl, const f32x4 (&acc)[NI][4],
                                           int w, int l) {
  const int tr0 = (w >> 1) * (16 * NI), tc0 = (w & 1) * 64;
  #pragma unroll
  for (int i = 0; i < NI; ++i) {
    const int rowb = tr0 + i*16 + ((l >> 4) << 2);
    #pragma unroll
    for (int j = 0; j < 4; ++j) {
      const int colg = tc0 + j*16 + (l & 15);
      f16x4 hh, hl;
      #pragma unroll
      for (int r = 0; r < 4; ++r) {
        float v = acc[i][j][r];
        f16 hi = (f16)v;
        hh[r] = hi; hl[r] = (f16)(v - (float)hi);
      }
      *(f16x4*)(bh + swz(colg, rowb)) = hh;
      *(f16x4*)(bl + swz(colg, rowb)) = hl;
    }
  }
}

// transpose writeback: v = acc + d0*I + d1*Uc + d2*U2c + d3*U3c (chunks in regs)
template<int NI>
__device__ __forceinline__ void wb_t_combo4(f16* buf, const f32x4 (&acc)[NI][4],
                                            const f16x4* Uc, const f16x4* U2c, const f16x4* U3c,
                                            int w, int l, float d0, float d1, float d2, float d3) {
  const int tr0 = (w >> 1) * (16 * NI), tc0 = (w & 1) * 64;
  #pragma unroll
  for (int i = 0; i < NI; ++i) {
    const int rowb = tr0 + i*16 + ((l >> 4) << 2);
    #pragma unroll
    for (int j = 0; j < 4; ++j) {
      const int colg = tc0 + j*16 + (l & 15);
      f16x4 h;
      #pragma unroll
      for (int r = 0; r < 4; ++r) {
        float v = acc[i][j][r] + d1 * (float)Uc[i*4+j][r] + d2 * (float)U2c[i*4+j][r]
                               + d3 * (float)U3c[i*4+j][r];
        if (rowb + r == colg) v += d0;
        h[r] = (f16)v;
      }
      *(f16x4*)(buf + swz(colg, rowb)) = h;
    }
  }
}

// transpose writeback with combo read from LDS buffers C1,C2
template<int NI>
__device__ __forceinline__ void wb_t_gc(f16* buf, const f32x4 (&acc)[NI][4],
                                        const f16* C1, const f16* C2,
                                        int w, int l, float d0, float d1, float d2) {
  const int tr0 = (w >> 1) * (16 * NI), tc0 = (w & 1) * 64;
  #pragma unroll
  for (int i = 0; i < NI; ++i) {
    const int rowb = tr0 + i*16 + ((l >> 4) << 2);
    #pragma unroll
    for (int j = 0; j < 4; ++j) {
      const int colg = tc0 + j*16 + (l & 15);
      f16x4 c1 = *(const f16x4*)(C1 + swz(colg, rowb));
      f16x4 c2 = *(const f16x4*)(C2 + swz(colg, rowb));
      f16x4 h;
      #pragma unroll
      for (int r = 0; r < 4; ++r) {
        float v = acc[i][j][r] + d1 * (float)c1[r] + d2 * (float)c2[r];
        if (rowb + r == colg) v += d0;
        h[r] = (f16)v;
      }
      *(f16x4*)(buf + swz(colg, rowb)) = h;
    }
  }
}

// async stage: raw fp32 X (64KB) -> LDS buffers b1(32KB)+b3(32KB), linear
__device__ __forceinline__ void stage_issue(const float* __restrict__ Xn,
                                            f16* b1, f16* b3, int t) {
  const int w = t >> 6, l = t & 63;
  #pragma unroll
  for (int q = 0; q < 8; ++q) {
    const int cb = (w * 8 + q) * 64;            // base 16B-chunk (wave-uniform)
    const float* src = Xn + (size_t)(cb + l) * 4;
    f16* dstbase = (cb < 2048) ? (f16*)((char*)b1 + (size_t)cb * 16)
                               : (f16*)((char*)b3 + (size_t)(cb - 2048) * 16);
    __builtin_amdgcn_global_load_lds(
        (const __attribute__((address_space(1))) unsigned int*)src,
        (__attribute__((address_space(3))) unsigned int*)dstbase, 16, 0, 0);
  }
}
// staged raw fp32 (b1,b3) -> swizzled f16 dst
__device__ __forceinline__ void convert_staged(const f16* b1, const f16* b3, f16* dst, int t) {
  for (int g = t; g < 2048; g += 512) {
    int r = g >> 4, c8 = (g & 15) << 3;
    int f0 = g * 8;
    const float* src = (f0 < 8192) ? (const float*)b1 + f0 : (const float*)b3 + (f0 - 8192);
    float4 v0 = *(const float4*)src;
    float4 v1 = *(const float4*)(src + 4);
    f16x8 h;
    h[0]=(f16)v0.x; h[1]=(f16)v0.y; h[2]=(f16)v0.z; h[3]=(f16)v0.w;
    h[4]=(f16)v1.x; h[5]=(f16)v1.y; h[6]=(f16)v1.z; h[7]=(f16)v1.w;
    *(f16x8*)(dst + swz(r, c8)) = h;
  }
}

// =================== phase A: batch mean (float4) ===================
__global__ void k_mean_part(const float* __restrict__ X, float* __restrict__ part, int nper) {
  int e4 = blockIdx.x * 256 + threadIdx.x;     // grid (16,16): 4096 float4/matrix
  int bc = blockIdx.y;
  const float4* p = (const float4*)X + (size_t)bc * nper * 4096 + e4;
  float4 s = {0.f, 0.f, 0.f, 0.f};
  for (int b = 0; b < nper; ++b) {
    float4 v = p[(size_t)b * 4096];
    s.x += v.x; s.y += v.y; s.z += v.z; s.w += v.w;
  }
  ((float4*)part)[(size_t)bc * 4096 + e4] = s;
}
__global__ void k_mean_fin(const float* __restrict__ part, float* __restrict__ M0, float scale) {
  int e4 = blockIdx.x * 256 + threadIdx.x;     // 16 blocks
  float4 s = {0.f, 0.f, 0.f, 0.f};
  for (int c = 0; c < 16; ++c) {
    float4 v = ((const float4*)part)[(size_t)c * 4096 + e4];
    s.x += v.x; s.y += v.y; s.z += v.z; s.w += v.w;
  }
  s.x *= scale; s.y *= scale; s.z *= scale; s.w *= scale;
  ((float4*)M0)[e4] = s;
}

// =================== kB: Cp=M0^{-1/2} (split), R=M0^{1/2} (split) ===========
// VGPR budget: pin exactly 2 waves/EU (forced anyway by 512thr/1blk-by-LDS)
// -> allocator gets 512-reg-pool/2 = 256 VGPRs.  __launch_bounds__ failed to
// do this (r3/r4: allocator stayed at 128 -> spill -> 410MB scratch HBM).
#define ATTR512 __attribute__((amdgpu_flat_work_group_size(512, 512), amdgpu_waves_per_eu(2, 2)))

__global__ ATTR512 void kB(
    const float* __restrict__ M0,
    f16* __restrict__ Cph, f16* __restrict__ Cpl,
    f16* __restrict__ Rh,  f16* __restrict__ Rl) {
  __shared__ __align__(16) f16 A1[NN], A2[NN], A3[NN], A4[NN];
  __shared__ float red[128];
  __shared__ float sS;
  const int t = threadIdx.x, w = t >> 6, l = t & 63;
  if (t < 128) red[t] = M0[t * 129];
  __syncthreads();
  for (int s = 64; s > 0; s >>= 1) { if (t < s) red[t] += red[t + s]; __syncthreads(); }
  if (t == 0) sS = red[0] / 128.f;
  __syncthreads();
  const float s = sS, inv = 1.f / s;
  for (int e = t; e < NN; e += 512) {
    int r = e >> 7, c = e & 127;
    A1[swz(r, c)] = (f16)(M0[e] * inv - (r == c ? 1.f : 0.f));
  }
  __syncthreads();
  f32x4 acc[2][4];
  zero_acc<2>(acc); mm_lds<2>(A1, A1, acc, w, l); wb_t<2>(A2, acc, w, l, 1.f, 0.f); __syncthreads();
  zero_acc<2>(acc); mm_lds<2>(A2, A1, acc, w, l); wb_t<2>(A3, acc, w, l, 1.f, 0.f); __syncthreads();
  zero_acc<2>(acc); mm_lds<2>(A2, A2, acc, w, l); wb_t<2>(A4, acc, w, l, 1.f, 0.f); __syncthreads();
  const float rs = sqrtf(s), irs = 1.f / rs;
  for (int e = t; e < NN; e += 512) {
    int r = e >> 7, c = e & 127; int ix = swz(r, c);
    float a1 = (float)A1[ix], a2 = (float)A2[ix], a3 = (float)A3[ix], a4 = (float)A4[ix];
    float d = (r == c) ? 1.f : 0.f;
    float cp = (d - 0.5f*a1 + 0.375f*a2 - 0.3125f*a3 + 0.2734375f*a4) * irs;
    float rr = (d + 0.5f*a1 - 0.125f*a2 + 0.0625f*a3 - 0.0390625f*a4) * rs;
    f16 ch = (f16)cp; Cph[e] = ch; Cpl[e] = (f16)(cp - (float)ch);
    f16 rh = (f16)rr; Rh[e]  = rh; Rl[e]  = (f16)(rr - (float)rh);
  }
}

// ===== phase C: sum of matrix logs (deg-31 poly, PS stride U^4, 12 mm/matrix)
__global__ ATTR512 void k_batch_log(
    const float* __restrict__ X, const f16* __restrict__ Cph, const f16* __restrict__ Cpl,
    float* __restrict__ Ppart, int per_blk) {
  __shared__ __align__(16) f16 S0[NN], S1[NN], S2[NN], S3[NN];   // 128 KB
  const int t = threadIdx.x, w = t >> 6, l = t & 63;
  f32x4 lsum[2][4]; zero_acc<2>(lsum);
  f32x4 acc[2][4];
  for (int m = 0; m < per_blk; ++m) {
    const size_t b = (size_t)blockIdx.x * per_blk + m;
    if (m == 0) {
      load_g2l(X + b * NN, S0, t, 512);
    } else {
      asm volatile("s_waitcnt vmcnt(0)" ::: "memory");
      __syncthreads();                      // staged X visible everywhere; S0 free
      convert_staged(S1, S3, S0, t);
    }
    {
      f16x8 bch[16], bcl[16];
      pre_bf_glb(Cph, bch, w, l);
      pre_bf_glb(Cpl, bcl, w, l);
      __syncthreads();                      // X in S0 ready
      // pass1: acc = X*Cp^T -> store^T = Cp*X = T -> S1
      zero_acc<2>(acc); mm_pre2<2>(S0, bch, bcl, acc, w, l);
      wb_t<2>(S1, acc, w, l, 1.f, 0.f); __syncthreads();
      // pass2: acc = T*Cp -> U = (B0 - c I)/w -> S0
      zero_acc<2>(acc); mm_pre2<2>(S1, bch, bcl, acc, w, l);
      wb_t<2>(S0, acc, w, l, 1.f / WW, -CC / WW); __syncthreads();
    }
    // U2 -> S2, U3 -> S3, U4 -> S1
    zero_acc<2>(acc); mm_lds<2>(S0, S0, acc, w, l); wb_t<2>(S2, acc, w, l, 1.f, 0.f); __syncthreads();
    zero_acc<2>(acc); mm_lds<2>(S2, S0, acc, w, l); wb_t<2>(S3, acc, w, l, 1.f, 0.f); __syncthreads();
    zero_acc<2>(acc); mm_lds<2>(S2, S2, acc, w, l); wb_t<2>(S1, acc, w, l, 1.f, 0.f); __syncthreads();
    // register preloads: U4 fragments; U,U2,U3 combo chunks
    f16x8 bfr[16]; f16x4 Uc[8], U2c[8], U3c[8];
    pre_bf_lds(S1, bfr, w, l);
    pre_chunks<2>(S0, Uc, w, l);
    pre_chunks<2>(S2, U2c, w, l);
    pre_chunks<2>(S3, U3c, w, l);
    __syncthreads();
    // H-init: g7 = d28 I + d29 U + d30 U2 + d31 U3 -> S0 (in place over U)
    for (int g = t; g < 2048; g += 512) {
      int e0 = g * 8;
      f16x8 u  = *(const f16x8*)(S0 + e0);
      f16x8 u2 = *(const f16x8*)(S2 + e0);
      f16x8 u3 = *(const f16x8*)(S3 + e0);
      int r = e0 >> 7;
      int c0 = ((((e0 >> 3) & 15) ^ (r & 7)) << 3);
      f16x8 h;
      #pragma unroll
      for (int k = 0; k < 8; ++k) {
        float v = DKC.v[29] * (float)u[k] + DKC.v[30] * (float)u2[k] + DKC.v[31] * (float)u3[k];
        if (r == c0 + k) v += DKC.v[28];
        h[k] = (f16)v;
      }
      *(f16x8*)(S0 + e0) = h;
    }
    __syncthreads();
    // prefetch next X into dead S1/S3 (raw fp32) while Horner runs
    if (m + 1 < per_blk) stage_issue(X + (b + 1) * NN, S1, S3, t);
    // Horner j=6..1 ping-pong S0 <-> S2 (1 barrier/pass)
    f16* pc = S0; f16* pn = S2;
    #pragma unroll
    for (int jj = 6; jj >= 1; --jj) {
      zero_acc<2>(acc);
      mm_pre<2>(pc, bfr, acc, w, l);
      wb_t_combo4<2>(pn, acc, Uc, U2c, U3c, w, l,
                     DKC.v[4*jj], DKC.v[4*jj+1], DKC.v[4*jj+2], DKC.v[4*jj+3]);
      __syncthreads();
      f16* tmp = pc; pc = pn; pn = tmp;
    }
    // final block j=0: accumulate into lsum, no store
    zero_acc<2>(acc);
    mm_pre<2>(pc, bfr, acc, w, l);
    {
      const int tr0 = (w >> 1) * 32, tc0 = (w & 1) * 64;
      #pragma unroll
      for (int i = 0; i < 2; ++i) {
        const int rowb = tr0 + i*16 + ((l >> 4) << 2);
        #pragma unroll
        for (int j = 0; j < 4; ++j) {
          const int colg = tc0 + j*16 + (l & 15);
          #pragma unroll
          for (int r = 0; r < 4; ++r) {
            float v = acc[i][j][r] + DKC.v[1] * (float)Uc[i*4+j][r]
                    + DKC.v[2] * (float)U2c[i*4+j][r] + DKC.v[3] * (float)U3c[i*4+j][r];
            if (rowb + r == colg) v += DKC.v[0];
            lsum[i][j][r] += v;
          }
        }
      }
    }
    __syncthreads();
  }
  // store partials (sum of logs is symmetric -> transposed float4 store is exact)
  float* pp = Ppart + (size_t)blockIdx.x * NN;
  const int tr0 = (w >> 1) * 32, tc0 = (w & 1) * 64;
  #pragma unroll
  for (int i = 0; i < 2; ++i) {
    const int rowb = tr0 + i*16 + ((l >> 4) << 2);
    #pragma unroll
    for (int j = 0; j < 4; ++j) {
      const int colg = tc0 + j*16 + (l & 15);
      *(f32x4*)(pp + colg * 128 + rowb) = lsum[i][j];
    }
  }
}

__global__ void k_reduceP(const float* __restrict__ Pp, float* __restrict__ P, float invBn) {
  int e4 = blockIdx.x * 256 + threadIdx.x;    // 16 blocks
  f32x4 s = {0.f, 0.f, 0.f, 0.f};
  for (int b = 0; b < 256; ++b) {
    f32x4 v = ((const f32x4*)Pp)[(size_t)b * 4096 + e4];
    s = s + v;
  }
  ((f32x4*)P)[e4] = s * invBn;
}

// ========= kD: E=exp(P) (deg-8), BM=R E R, S=BM^{-1/2}, T=mean^{1/2}, G=T*S ==
__global__ ATTR512 void kD(
    const float* __restrict__ P, const float* __restrict__ mean,
    const f16* __restrict__ Rh, const f16* __restrict__ Rl,
    f16* __restrict__ Gh, f16* __restrict__ Gl) {
  __shared__ __align__(16) f16 B1[NN], B2[NN], B3[NN], B4[NN];
  __shared__ float red[128];
  __shared__ float sv;
  const int t = threadIdx.x, w = t >> 6, l = t & 63;
  f32x4 acc[2][4];
  // mu = tr(P)/128
  if (t < 128) red[t] = P[t * 129];
  __syncthreads();
  for (int s = 64; s > 0; s >>= 1) { if (t < s) red[t] += red[t + s]; __syncthreads(); }
  if (t == 0) sv = red[0] / 128.f;
  __syncthreads();
  const float mu = sv;
  // D -> B1
  for (int e = t; e < NN; e += 512) {
    int r = e >> 7, c = e & 127;
    B1[swz(r, c)] = (f16)(P[e] - (r == c ? mu : 0.f));
  }
  __syncthreads();
  // D2 -> B2, D3 -> B3
  zero_acc<2>(acc); mm_lds<2>(B1, B1, acc, w, l); wb_t<2>(B2, acc, w, l, 1.f, 0.f); __syncthreads();
  zero_acc<2>(acc); mm_lds<2>(B2, B1, acc, w, l); wb_t<2>(B3, acc, w, l, 1.f, 0.f); __syncthreads();
  // T = g2 = I/720 + D/5040 + D2/40320 -> B4
  for (int g = t; g < 2048; g += 512) {
    int e0 = g * 8;
    f16x8 d1 = *(const f16x8*)(B1 + e0);
    f16x8 d2 = *(const f16x8*)(B2 + e0);
    int r = e0 >> 7;
    int c0 = ((((e0 >> 3) & 15) ^ (r & 7)) << 3);
    f16x8 h;
    #pragma unroll
    for (int k = 0; k < 8; ++k) {
      float v = (1.f/5040.f) * (float)d1[k] + (1.f/40320.f) * (float)d2[k];
      if (r == c0 + k) v += (1.f/720.f);
      h[k] = (f16)v;
    }
    *(f16x8*)(B4 + e0) = h;
  }
  __syncthreads();
  // T <- D3*T + g1 (g1 = I/6 + D/24 + D2/120), in place B4 (needs mid barrier)
  zero_acc<2>(acc); mm_lds<2>(B3, B4, acc, w, l); __syncthreads();
  wb_t_gc<2>(B4, acc, B1, B2, w, l, 1.f/6.f, 1.f/24.f, 1.f/120.f);
  __syncthreads();
  // E = e^mu * (D3*T + I + D + D2/2): split -> Eh:B2, El:B3
  zero_acc<2>(acc); mm_lds<2>(B3, B4, acc, w, l); __syncthreads();
  {
    const float emu = expf(mu);
    const int tr0 = (w >> 1) * 32, tc0 = (w & 1) * 64;
    #pragma unroll
    for (int i = 0; i < 2; ++i) {
      const int rowb = tr0 + i*16 + ((l >> 4) << 2);
      #pragma unroll
      for (int j = 0; j < 4; ++j) {
        const int colg = tc0 + j*16 + (l & 15);
        f16x4 dc  = *(const f16x4*)(B1 + swz(colg, rowb));
        f16x4 d2c = *(const f16x4*)(B2 + swz(colg, rowb));
        f16x4 hh, hl;
        #pragma unroll
        for (int r = 0; r < 4; ++r) {
          float v = acc[i][j][r] + (float)dc[r] + 0.5f * (float)d2c[r];
          if (rowb + r == colg) v += 1.f;
          v *= emu;
          f16 hi = (f16)v; hh[r] = hi; hl[r] = (f16)(v - (float)hi);
        }
        *(f16x4*)(B2 + swz(colg, rowb)) = hh;
        *(f16x4*)(B3 + swz(colg, rowb)) = hl;
      }
    }
  }
  __syncthreads();
  // R into LDS
  load_g2l_h(Rh, B1, t, 512);
  load_g2l_h(Rl, B4, t, 512);
  __syncthreads();
  // T1 = E*R (buffer holds (E*R)^T): split -> B2,B3
  zero_acc<2>(acc);
  mm_lds<2>(B2, B1, acc, w, l);   // Eh*Rh
  mm_lds<2>(B2, B4, acc, w, l);   // Eh*Rl
  mm_lds<2>(B3, B1, acc, w, l);   // El*Rh
  __syncthreads();
  wb_t_split<2>(B2, B3, acc, w, l);
  __syncthreads();
  // BM = R*T1: A=R, B̂buf=(E*R)^T -> split B2,B3 (BM symmetric)
  zero_acc<2>(acc);
  mm_lds<2>(B1, B2, acc, w, l);   // Rh*T1h
  mm_lds<2>(B1, B3, acc, w, l);   // Rh*T1l
  mm_lds<2>(B4, B2, acc, w, l);   // Rl*T1h
  __syncthreads();
  wb_t_split<2>(B2, B3, acc, w, l);
  __syncthreads();
  // s2 = tr(BM)/128
  if (t < 128) red[t] = (float)B2[swz(t, t)] + (float)B3[swz(t, t)];
  __syncthreads();
  for (int s = 64; s > 0; s >>= 1) { if (t < s) red[t] += red[t + s]; __syncthreads(); }
  if (t == 0) sv = red[0] / 128.f;
  __syncthreads();
  const float s2 = sv, inv2 = 1.f / s2;
  // F = BM/s2 - I -> B1
  for (int e = t; e < NN; e += 512) {
    int r = e >> 7, c = e & 127; int ix = swz(r, c);
    B1[ix] = (f16)(((float)B2[ix] + (float)B3[ix]) * inv2 - (r == c ? 1.f : 0.f));
  }
  __syncthreads();
  // F2 -> B4, F3 -> B2, F4 -> B3
  zero_acc<2>(acc); mm_lds<2>(B1, B1, acc, w, l); wb_t<2>(B4, acc, w, l, 1.f, 0.f); __syncthreads();
  zero_acc<2>(acc); mm_lds<2>(B4, B1, acc, w, l); wb_t<2>(B2, acc, w, l, 1.f, 0.f); __syncthreads();
  zero_acc<2>(acc); mm_lds<2>(B4, B4, acc, w, l); wb_t<2>(B3, acc, w, l, 1.f, 0.f); __syncthreads();
  // S = (I - F/2 + 3F2/8 - 5F3/16 + 35F4/128)/sqrt(s2): split -> Sh:B1, Sl:B4
  {
    const float is2 = 1.f / sqrtf(s2);
    for (int e = t; e < NN; e += 512) {
      int r = e >> 7, c = e & 127; int ix = swz(r, c);
      float f1 = (float)B1[ix], f2 = (float)B4[ix], f3 = (float)B2[ix], f4 = (float)B3[ix];
      float d = (r == c) ? 1.f : 0.f;
      float vv = (d - 0.5f*f1 + 0.375f*f2 - 0.3125f*f3 + 0.2734375f*f4) * is2;
      f16 hi = (f16)vv;
      B1[ix] = hi; B4[ix] = (f16)(vv - (float)hi);
    }
  }
  __syncthreads();
  // T_sqrt = mean^{1/2}: s3 = tr(mean)/128, M -> B2, M2 -> B3
  if (t < 128) red[t] = mean[t * 129];
  __syncthreads();
  for (int s = 64; s > 0; s >>= 1) { if (t < s) red[t] += red[t + s]; __syncthreads(); }
  if (t == 0) sv = red[0] / 128.f;
  __syncthreads();
  const float s3 = sv, inv3 = 1.f / s3;
  for (int e = t; e < NN; e += 512) {
    int r = e >> 7, c = e & 127;
    B2[swz(r, c)] = (f16)(mean[e] * inv3 - (r == c ? 1.f : 0.f));
  }
  __syncthreads();
  zero_acc<2>(acc); mm_lds<2>(B2, B2, acc, w, l); __syncthreads();
  wb_t<2>(B3, acc, w, l, 1.f, 0.f); __syncthreads();
  {
    const float rs3 = sqrtf(s3);
    for (int e = t; e < NN; e += 512) {
      int r = e >> 7, c = e & 127; int ix = swz(r, c);
      float m1 = (float)B2[ix], m2 = (float)B3[ix];
      float d = (r == c) ? 1.f : 0.f;
      float vv = (d + 0.5f*m1 - 0.125f*m2) * rs3;
      f16 hi = (f16)vv;
      B2[ix] = hi; B3[ix] = (f16)(vv - (float)hi);
    }
  }
  __syncthreads();
  // G = T*S: acc = S*T (A=S: B1,B4; B̂=T: B2,B3), store transposed -> G (global)
  zero_acc<2>(acc);
  mm_lds<2>(B1, B2, acc, w, l);   // Sh*Th
  mm_lds<2>(B1, B3, acc, w, l);   // Sh*Tl
  mm_lds<2>(B4, B2, acc, w, l);   // Sl*Th
  {
    const int tr0 = (w >> 1) * 32, tc0 = (w & 1) * 64;
    #pragma unroll
    for (int i = 0; i < 2; ++i) {
      const int rowb = tr0 + i*16 + ((l >> 4) << 2);
      #pragma unroll
      for (int j = 0; j < 4; ++j) {
        const int colg = tc0 + j*16 + (l & 15);
        f16x4 hh, hl;
        #pragma unroll
        for (int r = 0; r < 4; ++r) {
          float v = acc[i][j][r];
          f16 hi = (f16)v; hh[r] = hi; hl[r] = (f16)(v - (float)hi);
        }
        *(f16x4*)(Gh + colg * 128 + rowb) = hh;
        *(f16x4*)(Gl + colg * 128 + rowb) = hl;
      }
    }
  }
}

// =================== phase E: Xn = G * X * G^T ===================
// 256 thr, 64KB LDS -> 2 blocks/CU = 2 waves/EU; pin waves_per_eu(2,2) so
// the allocator budgets 256 VGPRs (demand: bgh+bgl 128 + acc 64 + temps).
__global__ __attribute__((amdgpu_flat_work_group_size(256, 256), amdgpu_waves_per_eu(2, 2)))
void k_apply(
    const float* __restrict__ X, const f16* __restrict__ Gh, const f16* __restrict__ Gl,
    float* __restrict__ Out, int per_blk) {
  __shared__ __align__(16) f16 SX[NN], ST[NN];
  const int t = threadIdx.x, w = t >> 6, l = t & 63;
  f16x8 bgh[16], bgl[16];
  pre_bf_glb(Gh, bgh, w, l);
  pre_bf_glb(Gl, bgl, w, l);
  f32x4 acc[4][4];
  for (int m = 0; m < per_blk; ++m) {
    const size_t b = (size_t)blockIdx.x * per_blk + m;
    load_g2l(X + b * NN, SX, t, 256);
    __syncthreads();
    // acc = X*G^T -> store^T = G*X = T
    zero_acc<4>(acc); mm_pre2<4>(SX, bgh, bgl, acc, w, l); __syncthreads();
    wb_t<4>(ST, acc, w, l, 1.f, 0.f); __syncthreads();
    // acc = T*G^T = G X G^T -> global (symmetric: transposed float4 store exact)
    zero_acc<4>(acc); mm_pre2<4>(ST, bgh, bgl, acc, w, l);
    float* O = Out + b * NN;
    const int tr0 = (w >> 1) * 64, tc0 = (w & 1) * 64;
    #pragma unroll
    for (int i = 0; i < 4; ++i) {
      const int rowb = tr0 + i*16 + ((l >> 4) << 2);
      #pragma unroll
      for (int j = 0; j < 4; ++j) {
        const int colg = tc0 + j*16 + (l & 15);
        *(f32x4*)(O + colg * 128 + rowb) = acc[i][j];
      }
    }
    __syncthreads();
  }
}

// =================== host ===================
extern "C" void kernel_launch(void* const* d_in, const int* in_sizes, int n_in,
                              void* d_out, int out_size, void* d_ws, size_t ws_size,
                              hipStream_t stream) {
  const float* X    = (const float*)d_in[0];
  const float* mean = (const float*)d_in[1];
  // d_in[2] (running_mean) mathematically unused: eta=1.0 makes
  // rm_sqrt @ powm(rm_invsqrt@BM@rm_invsqrt, 1) @ rm_sqrt == BM for ANY SPD rm.
  const int Bn = in_sizes[0] / NN;       // 2048

  float* wsf = (float*)d_ws;
  float* M0 = wsf;
  float* P  = wsf + NN;
  f16* hbase = (f16*)(wsf + 2 * (size_t)NN);
  f16 *Cph = hbase,            *Cpl = hbase + NN;
  f16 *Rh  = hbase + 2 * NN,   *Rl  = hbase + 3 * NN;
  f16 *Gh  = hbase + 4 * NN,   *Gl  = hbase + 5 * NN;
  float* Ppart = wsf + 5 * (size_t)NN;   // 256 slots (16 MB); also mean partials

  k_mean_part<<<dim3(16, 16), 256, 0, stream>>>(X, Ppart, Bn / 16);
  k_mean_fin<<<16, 256, 0, stream>>>(Ppart, M0, 1.f / (float)Bn);
  kB<<<1, 512, 0, stream>>>(M0, Cph, Cpl, Rh, Rl);
  k_batch_log<<<256, 512, 0, stream>>>(X, Cph, Cpl, Ppart, Bn / 256);
  k_reduceP<<<16, 256, 0, stream>>>(Ppart, P, 1.f / (float)Bn);
  kD<<<1, 512, 0, stream>>>(P, mean, Rh, Rl, Gh, Gl);
  k_apply<<<512, 256, 0, stream>>>(X, Gh, Gl, (float*)d_out, Bn / 512);
}

// Round 7
// 364.521 us; speedup vs baseline: 1.3813x; 1.3679x over previous
//
#include <hip/hip_runtime.h>

typedef _Float16 f16;
typedef _Float16 f16x8 __attribute__((ext_vector_type(8)));
typedef _Float16 f16x4 __attribute__((ext_vector_type(4)));
typedef float    f32x4 __attribute__((ext_vector_type(4)));

#define NN 16384   // 128*128

// log-range constants: lambda(B0) in [0.33, 3.4] (hard: X>=0.5I, M0~1.5I)
#define CC 1.9f
#define WW 1.6f

struct DKA { float v[33]; };
__host__ __device__ constexpr DKA make_dk() {
  DKA d{};
  d.v[0] = 0.641853886172395f;  // ln(1.9)
  float q = 1.f;
  for (int k = 1; k < 33; ++k) { q *= (WW / CC); d.v[k] = ((k & 1) ? 1.f : -1.f) * q / (float)k; }
  return d;
}
__device__ constexpr DKA DKC = make_dk();

// ---------------- swizzled LDS index for 128x128 f16 (G4 XOR pattern) -------
__device__ __forceinline__ int swz(int r, int c) {
  return (r << 7) + ((((c >> 3) ^ (r & 7)) << 3) | (c & 7));
}

// load 128x128 fp32 (global) -> f16 swizzled LDS
__device__ __forceinline__ void load_g2l(const float* __restrict__ G, f16* buf, int t, int nt) {
  for (int ch = t; ch < 2048; ch += nt) {
    int r = ch >> 4, c8 = (ch & 15) << 3;
    const float* g = G + (r << 7) + c8;
    float4 v0 = *(const float4*)g;
    float4 v1 = *(const float4*)(g + 4);
    f16x8 h;
    h[0]=(f16)v0.x; h[1]=(f16)v0.y; h[2]=(f16)v0.z; h[3]=(f16)v0.w;
    h[4]=(f16)v1.x; h[5]=(f16)v1.y; h[6]=(f16)v1.z; h[7]=(f16)v1.w;
    *(f16x8*)(buf + swz(r, c8)) = h;
  }
}
// rows 64..127 only (second half; first half comes from the S4 prefetch)
__device__ __forceinline__ void load_g2l_rows64(const float* __restrict__ G, f16* buf, int t) {
  for (int ch = 1024 + t; ch < 2048; ch += 512) {
    int r = ch >> 4, c8 = (ch & 15) << 3;
    const float* g = G + (r << 7) + c8;
    float4 v0 = *(const float4*)g;
    float4 v1 = *(const float4*)(g + 4);
    f16x8 h;
    h[0]=(f16)v0.x; h[1]=(f16)v0.y; h[2]=(f16)v0.z; h[3]=(f16)v0.w;
    h[4]=(f16)v1.x; h[5]=(f16)v1.y; h[6]=(f16)v1.z; h[7]=(f16)v1.w;
    *(f16x8*)(buf + swz(r, c8)) = h;
  }
}
// load 128x128 f16 (global, row-major) -> swizzled LDS
__device__ __forceinline__ void load_g2l_h(const f16* __restrict__ G, f16* buf, int t, int nt) {
  for (int ch = t; ch < 2048; ch += nt) {
    int r = ch >> 4, c8 = (ch & 15) << 3;
    *(f16x8*)(buf + swz(r, c8)) = *(const f16x8*)(G + (r << 7) + c8);
  }
}
// async prefetch: raw fp32 rows 0..63 of next X (32KB = 2048 x 16B chunks)
// -> S4 (linear).  8 waves x 4 issues x 64 lanes x 16B = 32KB exactly.
// (r6 BUG: single issue covered only 8KB -> 24KB garbage -> f16 overflow -> NaN)
__device__ __forceinline__ void stage_half(const float* __restrict__ Xn, f16* s4, int t) {
  const int w = t >> 6, l = t & 63;
  #pragma unroll
  for (int q = 0; q < 4; ++q) {
    const int cb = (w * 4 + q) * 64;           // wave-uniform 16B-chunk base
    const float* src = Xn + (size_t)(cb + l) * 4;
    __builtin_amdgcn_global_load_lds(
        (const __attribute__((address_space(1))) unsigned int*)src,
        (__attribute__((address_space(3))) unsigned int*)((char*)s4 + (size_t)cb * 16), 16, 0, 0);
  }
}
// staged raw fp32 (S4) -> swizzled f16 rows 0..63 of dst
__device__ __forceinline__ void convert_half(const f16* s4, f16* dst, int t) {
  for (int g = t; g < 1024; g += 512) {
    int r = g >> 4, c8 = (g & 15) << 3;
    const float* src = (const float*)s4 + g * 8;
    float4 v0 = *(const float4*)src;
    float4 v1 = *(const float4*)(src + 4);
    f16x8 h;
    h[0]=(f16)v0.x; h[1]=(f16)v0.y; h[2]=(f16)v0.z; h[3]=(f16)v0.w;
    h[4]=(f16)v1.x; h[5]=(f16)v1.y; h[6]=(f16)v1.z; h[7]=(f16)v1.w;
    *(f16x8*)(dst + swz(r, c8)) = h;
  }
}

template<int NI>
__device__ __forceinline__ void zero_acc(f32x4 (&acc)[NI][4]) {
  #pragma unroll
  for (int i = 0; i < NI; ++i)
    #pragma unroll
    for (int j = 0; j < 4; ++j) acc[i][j] = (f32x4){0.f, 0.f, 0.f, 0.f};
}

// acc += A * B̂^T, both from swizzled LDS (valid as A*B when B̂ symmetric)
template<int NI>
__device__ __forceinline__ void mm_lds(const f16* A, const f16* Bh,
                                       f32x4 (&acc)[NI][4], int w, int l) {
  const int tr0 = (w >> 1) * (16 * NI), tc0 = (w & 1) * 64;
  #pragma unroll
  for (int ks = 0; ks < 4; ++ks) {
    const int kb = ks * 32 + ((l >> 4) << 3);
    f16x8 af[NI], bf[4];
    #pragma unroll
    for (int i = 0; i < NI; ++i) af[i] = *(const f16x8*)(A  + swz(tr0 + i*16 + (l & 15), kb));
    #pragma unroll
    for (int j = 0; j < 4; ++j) bf[j] = *(const f16x8*)(Bh + swz(tc0 + j*16 + (l & 15), kb));
    #pragma unroll
    for (int i = 0; i < NI; ++i)
      #pragma unroll
      for (int j = 0; j < 4; ++j)
        acc[i][j] = __builtin_amdgcn_mfma_f32_16x16x32_f16(af[i], bf[j], acc[i][j], 0, 0, 0);
  }
}

// acc += A*(B1̂^T + B2̂^T), all from LDS, A-fragments read once (split-B hi+lo)
template<int NI>
__device__ __forceinline__ void mm_lds2b(const f16* A, const f16* B1, const f16* B2,
                                         f32x4 (&acc)[NI][4], int w, int l) {
  const int tr0 = (w >> 1) * (16 * NI), tc0 = (w & 1) * 64;
  #pragma unroll
  for (int ks = 0; ks < 4; ++ks) {
    const int kb = ks * 32 + ((l >> 4) << 3);
    f16x8 af[NI], b1[4], b2[4];
    #pragma unroll
    for (int i = 0; i < NI; ++i) af[i] = *(const f16x8*)(A  + swz(tr0 + i*16 + (l & 15), kb));
    #pragma unroll
    for (int j = 0; j < 4; ++j) {
      b1[j] = *(const f16x8*)(B1 + swz(tc0 + j*16 + (l & 15), kb));
      b2[j] = *(const f16x8*)(B2 + swz(tc0 + j*16 + (l & 15), kb));
    }
    #pragma unroll
    for (int i = 0; i < NI; ++i)
      #pragma unroll
      for (int j = 0; j < 4; ++j) {
        acc[i][j] = __builtin_amdgcn_mfma_f32_16x16x32_f16(af[i], b1[j], acc[i][j], 0, 0, 0);
        acc[i][j] = __builtin_amdgcn_mfma_f32_16x16x32_f16(af[i], b2[j], acc[i][j], 0, 0, 0);
      }
  }
}

// acc += A*(B1̂^T) + A*(B2̂^T), B̂ fragments preloaded in regs (k_apply only —
// there the G-fragments are loop-invariant ON PURPOSE and fit the 256-reg budget)
template<int NI>
__device__ __forceinline__ void mm_pre2(const f16* A, const f16x8* b1, const f16x8* b2,
                                        f32x4 (&acc)[NI][4], int w, int l) {
  const int tr0 = (w >> 1) * (16 * NI);
  #pragma unroll
  for (int ks = 0; ks < 4; ++ks) {
    const int kb = ks * 32 + ((l >> 4) << 3);
    f16x8 af[NI];
    #pragma unroll
    for (int i = 0; i < NI; ++i) af[i] = *(const f16x8*)(A + swz(tr0 + i*16 + (l & 15), kb));
    #pragma unroll
    for (int i = 0; i < NI; ++i)
      #pragma unroll
      for (int j = 0; j < 4; ++j) {
        acc[i][j] = __builtin_amdgcn_mfma_f32_16x16x32_f16(af[i], b1[ks*4+j], acc[i][j], 0, 0, 0);
        acc[i][j] = __builtin_amdgcn_mfma_f32_16x16x32_f16(af[i], b2[ks*4+j], acc[i][j], 0, 0, 0);
      }
  }
}
// preload B̂ fragments from row-major GLOBAL f16 (k_apply)
__device__ __forceinline__ void pre_bf_glb(const f16* __restrict__ B, f16x8* bfr, int w, int l) {
  const int tc0 = (w & 1) * 64;
  #pragma unroll
  for (int ks = 0; ks < 4; ++ks) {
    const int kb = ks * 32 + ((l >> 4) << 3);
    #pragma unroll
    for (int j = 0; j < 4; ++j)
      bfr[ks*4+j] = *(const f16x8*)(B + (tc0 + j*16 + (l & 15)) * 128 + kb);
  }
}
// preload output-position b64 chunks (transposed convention)
template<int NI>
__device__ __forceinline__ void pre_chunks(const f16* M, f16x4* Cc, int w, int l) {
  const int tr0 = (w >> 1) * (16 * NI), tc0 = (w & 1) * 64;
  #pragma unroll
  for (int i = 0; i < NI; ++i) {
    const int rowb = tr0 + i*16 + ((l >> 4) << 2);
    #pragma unroll
    for (int j = 0; j < 4; ++j)
      Cc[i*4+j] = *(const f16x4*)(M + swz(tc0 + j*16 + (l & 15), rowb));
  }
}

// transpose-packed writeback: buf[swz(col,row)] = alpha*acc + beta*[row==col]
template<int NI>
__device__ __forceinline__ void wb_t(f16* buf, const f32x4 (&acc)[NI][4], int w, int l,
                                     float alpha, float beta) {
  const int tr0 = (w >> 1) * (16 * NI), tc0 = (w & 1) * 64;
  #pragma unroll
  for (int i = 0; i < NI; ++i) {
    const int rowb = tr0 + i*16 + ((l >> 4) << 2);
    #pragma unroll
    for (int j = 0; j < 4; ++j) {
      const int colg = tc0 + j*16 + (l & 15);
      f16x4 h;
      #pragma unroll
      for (int r = 0; r < 4; ++r) {
        float v = alpha * acc[i][j][r];
        if (rowb + r == colg) v += beta;
        h[r] = (f16)v;
      }
      *(f16x4*)(buf + swz(colg, rowb)) = h;
    }
  }
}

// transpose-packed split writeback (hi+lo f16)
template<int NI>
__device__ __forceinline__ void wb_t_split(f16* bh, f16* bl, const f32x4 (&acc)[NI][4],
                                           int w, int l) {
  const int tr0 = (w >> 1) * (16 * NI), tc0 = (w & 1) * 64;
  #pragma unroll
  for (int i = 0; i < NI; ++i) {
    const int rowb = tr0 + i*16 + ((l >> 4) << 2);
    #pragma unroll
    for (int j = 0; j < 4; ++j) {
      const int colg = tc0 + j*16 + (l & 15);
      f16x4 hh, hl;
      #pragma unroll
      for (int r = 0; r < 4; ++r) {
        float v = acc[i][j][r];
        f16 hi = (f16)v;
        hh[r] = hi; hl[r] = (f16)(v - (float)hi);
      }
      *(f16x4*)(bh + swz(colg, rowb)) = hh;
      *(f16x4*)(bl + swz(colg, rowb)) = hl;
    }
  }
}

// transpose writeback: v = acc + d0*I + d1*Uc(reg) + d2*U2c(reg) + d3*U3(LDS C3)
template<int NI>
__device__ __forceinline__ void wb_t_combo3L(f16* buf, const f32x4 (&acc)[NI][4],
                                             const f16x4* Uc, const f16x4* U2c, const f16* C3,
                                             int w, int l, float d0, float d1, float d2, float d3) {
  const int tr0 = (w >> 1) * (16 * NI), tc0 = (w & 1) * 64;
  #pragma unroll
  for (int i = 0; i < NI; ++i) {
    const int rowb = tr0 + i*16 + ((l >> 4) << 2);
    #pragma unroll
    for (int j = 0; j < 4; ++j) {
      const int colg = tc0 + j*16 + (l & 15);
      f16x4 c3 = *(const f16x4*)(C3 + swz(colg, rowb));
      f16x4 h;
      #pragma unroll
      for (int r = 0; r < 4; ++r) {
        float v = acc[i][j][r] + d1 * (float)Uc[i*4+j][r] + d2 * (float)U2c[i*4+j][r]
                               + d3 * (float)c3[r];
        if (rowb + r == colg) v += d0;
        h[r] = (f16)v;
      }
      *(f16x4*)(buf + swz(colg, rowb)) = h;
    }
  }
}

// transpose writeback with combo read from LDS buffers C1,C2 (kD)
template<int NI>
__device__ __forceinline__ void wb_t_gc(f16* buf, const f32x4 (&acc)[NI][4],
                                        const f16* C1, const f16* C2,
                                        int w, int l, float d0, float d1, float d2) {
  const int tr0 = (w >> 1) * (16 * NI), tc0 = (w & 1) * 64;
  #pragma unroll
  for (int i = 0; i < NI; ++i) {
    const int rowb = tr0 + i*16 + ((l >> 4) << 2);
    #pragma unroll
    for (int j = 0; j < 4; ++j) {
      const int colg = tc0 + j*16 + (l & 15);
      f16x4 c1 = *(const f16x4*)(C1 + swz(colg, rowb));
      f16x4 c2 = *(const f16x4*)(C2 + swz(colg, rowb));
      f16x4 h;
      #pragma unroll
      for (int r = 0; r < 4; ++r) {
        float v = acc[i][j][r] + d1 * (float)c1[r] + d2 * (float)c2[r];
        if (rowb + r == colg) v += d0;
        h[r] = (f16)v;
      }
      *(f16x4*)(buf + swz(colg, rowb)) = h;
    }
  }
}

// =================== phase A: batch mean (float4) ===================
__global__ void k_mean_part(const float* __restrict__ X, float* __restrict__ part, int nper) {
  int e4 = blockIdx.x * 256 + threadIdx.x;     // grid (16,16): 4096 float4/matrix
  int bc = blockIdx.y;
  const float4* p = (const float4*)X + (size_t)bc * nper * 4096 + e4;
  float4 s = {0.f, 0.f, 0.f, 0.f};
  for (int b = 0; b < nper; ++b) {
    float4 v = p[(size_t)b * 4096];
    s.x += v.x; s.y += v.y; s.z += v.z; s.w += v.w;
  }
  ((float4*)part)[(size_t)bc * 4096 + e4] = s;
}
__global__ void k_mean_fin(const float* __restrict__ part, float* __restrict__ M0, float scale) {
  int e4 = blockIdx.x * 256 + threadIdx.x;     // 16 blocks
  float4 s = {0.f, 0.f, 0.f, 0.f};
  for (int c = 0; c < 16; ++c) {
    float4 v = ((const float4*)part)[(size_t)c * 4096 + e4];
    s.x += v.x; s.y += v.y; s.z += v.z; s.w += v.w;
  }
  s.x *= scale; s.y *= scale; s.z *= scale; s.w *= scale;
  ((float4*)M0)[e4] = s;
}

// =================== kB: Cp=M0^{-1/2} (split), R=M0^{1/2} (split) ===========
__global__ __launch_bounds__(512) void kB(
    const float* __restrict__ M0,
    f16* __restrict__ Cph, f16* __restrict__ Cpl,
    f16* __restrict__ Rh,  f16* __restrict__ Rl) {
  __shared__ __align__(16) f16 A1[NN], A2[NN], A3[NN], A4[NN];
  __shared__ float red[128];
  __shared__ float sS;
  const int t = threadIdx.x, w = t >> 6, l = t & 63;
  if (t < 128) red[t] = M0[t * 129];
  __syncthreads();
  for (int s = 64; s > 0; s >>= 1) { if (t < s) red[t] += red[t + s]; __syncthreads(); }
  if (t == 0) sS = red[0] / 128.f;
  __syncthreads();
  const float s = sS, inv = 1.f / s;
  for (int e = t; e < NN; e += 512) {
    int r = e >> 7, c = e & 127;
    A1[swz(r, c)] = (f16)(M0[e] * inv - (r == c ? 1.f : 0.f));
  }
  __syncthreads();
  f32x4 acc[2][4];
  zero_acc<2>(acc); mm_lds<2>(A1, A1, acc, w, l); wb_t<2>(A2, acc, w, l, 1.f, 0.f); __syncthreads();
  zero_acc<2>(acc); mm_lds<2>(A2, A1, acc, w, l); wb_t<2>(A3, acc, w, l, 1.f, 0.f); __syncthreads();
  zero_acc<2>(acc); mm_lds<2>(A2, A2, acc, w, l); wb_t<2>(A4, acc, w, l, 1.f, 0.f); __syncthreads();
  const float rs = sqrtf(s), irs = 1.f / rs;
  for (int e = t; e < NN; e += 512) {
    int r = e >> 7, c = e & 127; int ix = swz(r, c);
    float a1 = (float)A1[ix], a2 = (float)A2[ix], a3 = (float)A3[ix], a4 = (float)A4[ix];
    float d = (r == c) ? 1.f : 0.f;
    float cp = (d - 0.5f*a1 + 0.375f*a2 - 0.3125f*a3 + 0.2734375f*a4) * irs;
    float rr = (d + 0.5f*a1 - 0.125f*a2 + 0.0625f*a3 - 0.0390625f*a4) * rs;
    f16 ch = (f16)cp; Cph[e] = ch; Cpl[e] = (f16)(cp - (float)ch);
    f16 rh = (f16)rr; Rh[e]  = rh; Rl[e]  = (f16)(rr - (float)rh);
  }
}

// ===== phase C: sum of matrix logs (deg-31 poly, PS stride U^4, 12 mm/matrix)
// All operands from LDS: no register preloads to hoist/spill (r3-r5 lesson:
// hoisted Cp fragments -> 300+ reg demand -> 410MB scratch HBM traffic).
// Reg demand: lsum 32 + acc 32(AGPR) + Uc/U2c 32 + addr ~= 110 -> fits 128.
__global__ __launch_bounds__(512) void k_batch_log(
    const float* __restrict__ X, const f16* __restrict__ Cph, const f16* __restrict__ Cpl,
    float* __restrict__ Ppart, int per_blk) {
  __shared__ __align__(16) f16 S0[NN], S1[NN], S2[NN], S3[NN], S4[NN];  // 160 KB (S4 = 32KB raw prefetch)
  const int t = threadIdx.x, w = t >> 6, l = t & 63;
  f32x4 lsum[2][4]; zero_acc<2>(lsum);
  f32x4 acc[2][4];
  for (int m = 0; m < per_blk; ++m) {
    const size_t b = (size_t)blockIdx.x * per_blk + m;
    if (m == 0) {
      load_g2l(X + b * NN, S0, t, 512);
    } else {
      asm volatile("s_waitcnt vmcnt(0)" ::: "memory");
      __syncthreads();                    // S4 prefetch visible everywhere
      convert_half(S4, S0, t);            // rows 0..63 from prefetch
      load_g2l_rows64(X + b * NN, S0, t); // rows 64..127 direct
    }
    load_g2l_h(Cph, S2, t, 512);          // Cp hi -> S2 (L2-resident)
    load_g2l_h(Cpl, S3, t, 512);          // Cp lo -> S3
    __syncthreads();
    // pass1: acc = X*Cp^T -> store^T = Cp*X = T -> S1
    zero_acc<2>(acc); mm_lds2b<2>(S0, S2, S3, acc, w, l);
    wb_t<2>(S1, acc, w, l, 1.f, 0.f); __syncthreads();
    // pass2: acc = T*Cp -> U = (B0 - c I)/w -> S0
    zero_acc<2>(acc); mm_lds2b<2>(S1, S2, S3, acc, w, l);
    wb_t<2>(S0, acc, w, l, 1.f / WW, -CC / WW); __syncthreads();
    // U2 -> S2 (Cp dead), U3 -> S3, U4 -> S1
    zero_acc<2>(acc); mm_lds<2>(S0, S0, acc, w, l); wb_t<2>(S2, acc, w, l, 1.f, 0.f); __syncthreads();
    zero_acc<2>(acc); mm_lds<2>(S2, S0, acc, w, l); wb_t<2>(S3, acc, w, l, 1.f, 0.f); __syncthreads();
    zero_acc<2>(acc); mm_lds<2>(S2, S2, acc, w, l); wb_t<2>(S1, acc, w, l, 1.f, 0.f); __syncthreads();
    // snapshot U,U2 combo chunks (their LDS buffers get recycled by ping-pong);
    // U3 chunks stay in LDS (S3 live through Horner)
    f16x4 Uc[8], U2c[8];
    pre_chunks<2>(S0, Uc, w, l);
    pre_chunks<2>(S2, U2c, w, l);
    __syncthreads();
    // H-init: g7 = d28 I + d29 U + d30 U2 + d31 U3 -> S0 (in place over U)
    for (int g = t; g < 2048; g += 512) {
      int e0 = g * 8;
      f16x8 u  = *(const f16x8*)(S0 + e0);
      f16x8 u2 = *(const f16x8*)(S2 + e0);
      f16x8 u3 = *(const f16x8*)(S3 + e0);
      int r = e0 >> 7;
      int c0 = ((((e0 >> 3) & 15) ^ (r & 7)) << 3);
      f16x8 h;
      #pragma unroll
      for (int k = 0; k < 8; ++k) {
        float v = DKC.v[29] * (float)u[k] + DKC.v[30] * (float)u2[k] + DKC.v[31] * (float)u3[k];
        if (r == c0 + k) v += DKC.v[28];
        h[k] = (f16)v;
      }
      *(f16x8*)(S0 + e0) = h;
    }
    __syncthreads();
    // prefetch rows 0..63 of next X into S4 (raw fp32) while Horner runs
    if (m + 1 < per_blk) stage_half(X + (b + 1) * NN, S4, t);
    // Horner j=6..1 ping-pong S0 <-> S2 (1 barrier/pass); B = U4 in S1 (LDS)
    f16* pc = S0; f16* pn = S2;
    #pragma unroll
    for (int jj = 6; jj >= 1; --jj) {
      zero_acc<2>(acc);
      mm_lds<2>(pc, S1, acc, w, l);
      wb_t_combo3L<2>(pn, acc, Uc, U2c, S3, w, l,
                      DKC.v[4*jj], DKC.v[4*jj+1], DKC.v[4*jj+2], DKC.v[4*jj+3]);
      __syncthreads();
      f16* tmp = pc; pc = pn; pn = tmp;
    }
    // final block j=0: accumulate into lsum, no store
    zero_acc<2>(acc);
    mm_lds<2>(pc, S1, acc, w, l);
    {
      const int tr0 = (w >> 1) * 32, tc0 = (w & 1) * 64;
      #pragma unroll
      for (int i = 0; i < 2; ++i) {
        const int rowb = tr0 + i*16 + ((l >> 4) << 2);
        #pragma unroll
        for (int j = 0; j < 4; ++j) {
          const int colg = tc0 + j*16 + (l & 15);
          f16x4 c3 = *(const f16x4*)(S3 + swz(colg, rowb));
          #pragma unroll
          for (int r = 0; r < 4; ++r) {
            float v = acc[i][j][r] + DKC.v[1] * (float)Uc[i*4+j][r]
                    + DKC.v[2] * (float)U2c[i*4+j][r] + DKC.v[3] * (float)c3[r];
            if (rowb + r == colg) v += DKC.v[0];
            lsum[i][j][r] += v;
          }
        }
      }
    }
    __syncthreads();
  }
  // store partials (sum of logs is symmetric -> transposed float4 store is exact)
  float* pp = Ppart + (size_t)blockIdx.x * NN;
  const int tr0 = (w >> 1) * 32, tc0 = (w & 1) * 64;
  #pragma unroll
  for (int i = 0; i < 2; ++i) {
    const int rowb = tr0 + i*16 + ((l >> 4) << 2);
    #pragma unroll
    for (int j = 0; j < 4; ++j) {
      const int colg = tc0 + j*16 + (l & 15);
      *(f32x4*)(pp + colg * 128 + rowb) = lsum[i][j];
    }
  }
}

__global__ void k_reduceP(const float* __restrict__ Pp, float* __restrict__ P, float invBn) {
  int e4 = blockIdx.x * 256 + threadIdx.x;    // 16 blocks
  f32x4 s = {0.f, 0.f, 0.f, 0.f};
  for (int b = 0; b < 256; ++b) {
    f32x4 v = ((const f32x4*)Pp)[(size_t)b * 4096 + e4];
    s = s + v;
  }
  ((f32x4*)P)[e4] = s * invBn;
}

// ========= kD: E=exp(P) (deg-8), BM=R E R, S=BM^{-1/2}, T=mean^{1/2}, G=T*S ==
__global__ __launch_bounds__(512) void kD(
    const float* __restrict__ P, const float* __restrict__ mean,
    const f16* __restrict__ Rh, const f16* __restrict__ Rl,
    f16* __restrict__ Gh, f16* __restrict__ Gl) {
  __shared__ __align__(16) f16 B1[NN], B2[NN], B3[NN], B4[NN];
  __shared__ float red[128];
  __shared__ float sv;
  const int t = threadIdx.x, w = t >> 6, l = t & 63;
  f32x4 acc[2][4];
  // mu = tr(P)/128
  if (t < 128) red[t] = P[t * 129];
  __syncthreads();
  for (int s = 64; s > 0; s >>= 1) { if (t < s) red[t] += red[t + s]; __syncthreads(); }
  if (t == 0) sv = red[0] / 128.f;
  __syncthreads();
  const float mu = sv;
  // D -> B1
  for (int e = t; e < NN; e += 512) {
    int r = e >> 7, c = e & 127;
    B1[swz(r, c)] = (f16)(P[e] - (r == c ? mu : 0.f));
  }
  __syncthreads();
  // D2 -> B2, D3 -> B3
  zero_acc<2>(acc); mm_lds<2>(B1, B1, acc, w, l); wb_t<2>(B2, acc, w, l, 1.f, 0.f); __syncthreads();
  zero_acc<2>(acc); mm_lds<2>(B2, B1, acc, w, l); wb_t<2>(B3, acc, w, l, 1.f, 0.f); __syncthreads();
  // T = g2 = I/720 + D/5040 + D2/40320 -> B4
  for (int g = t; g < 2048; g += 512) {
    int e0 = g * 8;
    f16x8 d1 = *(const f16x8*)(B1 + e0);
    f16x8 d2 = *(const f16x8*)(B2 + e0);
    int r = e0 >> 7;
    int c0 = ((((e0 >> 3) & 15) ^ (r & 7)) << 3);
    f16x8 h;
    #pragma unroll
    for (int k = 0; k < 8; ++k) {
      float v = (1.f/5040.f) * (float)d1[k] + (1.f/40320.f) * (float)d2[k];
      if (r == c0 + k) v += (1.f/720.f);
      h[k] = (f16)v;
    }
    *(f16x8*)(B4 + e0) = h;
  }
  __syncthreads();
  // T <- D3*T + g1 (g1 = I/6 + D/24 + D2/120), in place B4 (needs mid barrier)
  zero_acc<2>(acc); mm_lds<2>(B3, B4, acc, w, l); __syncthreads();
  wb_t_gc<2>(B4, acc, B1, B2, w, l, 1.f/6.f, 1.f/24.f, 1.f/120.f);
  __syncthreads();
  // E = e^mu * (D3*T + I + D + D2/2): split -> Eh:B2, El:B3
  zero_acc<2>(acc); mm_lds<2>(B3, B4, acc, w, l); __syncthreads();
  {
    const float emu = expf(mu);
    const int tr0 = (w >> 1) * 32, tc0 = (w & 1) * 64;
    #pragma unroll
    for (int i = 0; i < 2; ++i) {
      const int rowb = tr0 + i*16 + ((l >> 4) << 2);
      #pragma unroll
      for (int j = 0; j < 4; ++j) {
        const int colg = tc0 + j*16 + (l & 15);
        f16x4 dc  = *(const f16x4*)(B1 + swz(colg, rowb));
        f16x4 d2c = *(const f16x4*)(B2 + swz(colg, rowb));
        f16x4 hh, hl;
        #pragma unroll
        for (int r = 0; r < 4; ++r) {
          float v = acc[i][j][r] + (float)dc[r] + 0.5f * (float)d2c[r];
          if (rowb + r == colg) v += 1.f;
          v *= emu;
          f16 hi = (f16)v; hh[r] = hi; hl[r] = (f16)(v - (float)hi);
        }
        *(f16x4*)(B2 + swz(colg, rowb)) = hh;
        *(f16x4*)(B3 + swz(colg, rowb)) = hl;
      }
    }
  }
  __syncthreads();
  // R into LDS
  load_g2l_h(Rh, B1, t, 512);
  load_g2l_h(Rl, B4, t, 512);
  __syncthreads();
  // T1 = E*R (buffer holds (E*R)^T): split -> B2,B3
  zero_acc<2>(acc);
  mm_lds<2>(B2, B1, acc, w, l);   // Eh*Rh
  mm_lds<2>(B2, B4, acc, w, l);   // Eh*Rl
  mm_lds<2>(B3, B1, acc, w, l);   // El*Rh
  __syncthreads();
  wb_t_split<2>(B2, B3, acc, w, l);
  __syncthreads();
  // BM = R*T1: A=R, B̂buf=(E*R)^T -> split B2,B3 (BM symmetric)
  zero_acc<2>(acc);
  mm_lds<2>(B1, B2, acc, w, l);   // Rh*T1h
  mm_lds<2>(B1, B3, acc, w, l);   // Rh*T1l
  mm_lds<2>(B4, B2, acc, w, l);   // Rl*T1h
  __syncthreads();
  wb_t_split<2>(B2, B3, acc, w, l);
  __syncthreads();
  // s2 = tr(BM)/128
  if (t < 128) red[t] = (float)B2[swz(t, t)] + (float)B3[swz(t, t)];
  __syncthreads();
  for (int s = 64; s > 0; s >>= 1) { if (t < s) red[t] += red[t + s]; __syncthreads(); }
  if (t == 0) sv = red[0] / 128.f;
  __syncthreads();
  const float s2 = sv, inv2 = 1.f / s2;
  // F = BM/s2 - I -> B1
  for (int e = t; e < NN; e += 512) {
    int r = e >> 7, c = e & 127; int ix = swz(r, c);
    B1[ix] = (f16)(((float)B2[ix] + (float)B3[ix]) * inv2 - (r == c ? 1.f : 0.f));
  }
  __syncthreads();
  // F2 -> B4, F3 -> B2, F4 -> B3
  zero_acc<2>(acc); mm_lds<2>(B1, B1, acc, w, l); wb_t<2>(B4, acc, w, l, 1.f, 0.f); __syncthreads();
  zero_acc<2>(acc); mm_lds<2>(B4, B1, acc, w, l); wb_t<2>(B2, acc, w, l, 1.f, 0.f); __syncthreads();
  zero_acc<2>(acc); mm_lds<2>(B4, B4, acc, w, l); wb_t<2>(B3, acc, w, l, 1.f, 0.f); __syncthreads();
  // S = (I - F/2 + 3F2/8 - 5F3/16 + 35F4/128)/sqrt(s2): split -> Sh:B1, Sl:B4
  {
    const float is2 = 1.f / sqrtf(s2);
    for (int e = t; e < NN; e += 512) {
      int r = e >> 7, c = e & 127; int ix = swz(r, c);
      float f1 = (float)B1[ix], f2 = (float)B4[ix], f3 = (float)B2[ix], f4 = (float)B3[ix];
      float d = (r == c) ? 1.f : 0.f;
      float vv = (d - 0.5f*f1 + 0.375f*f2 - 0.3125f*f3 + 0.2734375f*f4) * is2;
      f16 hi = (f16)vv;
      B1[ix] = hi; B4[ix] = (f16)(vv - (float)hi);
    }
  }
  __syncthreads();
  // T_sqrt = mean^{1/2}: s3 = tr(mean)/128, M -> B2, M2 -> B3
  if (t < 128) red[t] = mean[t * 129];
  __syncthreads();
  for (int s = 64; s > 0; s >>= 1) { if (t < s) red[t] += red[t + s]; __syncthreads(); }
  if (t == 0) sv = red[0] / 128.f;
  __syncthreads();
  const float s3 = sv, inv3 = 1.f / s3;
  for (int e = t; e < NN; e += 512) {
    int r = e >> 7, c = e & 127;
    B2[swz(r, c)] = (f16)(mean[e] * inv3 - (r == c ? 1.f : 0.f));
  }
  __syncthreads();
  zero_acc<2>(acc); mm_lds<2>(B2, B2, acc, w, l); __syncthreads();
  wb_t<2>(B3, acc, w, l, 1.f, 0.f); __syncthreads();
  {
    const float rs3 = sqrtf(s3);
    for (int e = t; e < NN; e += 512) {
      int r = e >> 7, c = e & 127; int ix = swz(r, c);
      float m1 = (float)B2[ix], m2 = (float)B3[ix];
      float d = (r == c) ? 1.f : 0.f;
      float vv = (d + 0.5f*m1 - 0.125f*m2) * rs3;
      f16 hi = (f16)vv;
      B2[ix] = hi; B3[ix] = (f16)(vv - (float)hi);
    }
  }
  __syncthreads();
  // G = T*S: acc = S*T (A=S: B1,B4; B̂=T: B2,B3), store transposed -> G (global)
  zero_acc<2>(acc);
  mm_lds<2>(B1, B2, acc, w, l);   // Sh*Th
  mm_lds<2>(B1, B3, acc, w, l);   // Sh*Tl
  mm_lds<2>(B4, B2, acc, w, l);   // Sl*Th
  {
    const int tr0 = (w >> 1) * 32, tc0 = (w & 1) * 64;
    #pragma unroll
    for (int i = 0; i < 2; ++i) {
      const int rowb = tr0 + i*16 + ((l >> 4) << 2);
      #pragma unroll
      for (int j = 0; j < 4; ++j) {
        const int colg = tc0 + j*16 + (l & 15);
        f16x4 hh, hl;
        #pragma unroll
        for (int r = 0; r < 4; ++r) {
          float v = acc[i][j][r];
          f16 hi = (f16)v; hh[r] = hi; hl[r] = (f16)(v - (float)hi);
        }
        *(f16x4*)(Gh + colg * 128 + rowb) = hh;
        *(f16x4*)(Gl + colg * 128 + rowb) = hl;
      }
    }
  }
}

// =================== phase E: Xn = G * X * G^T ===================
// G-fragments deliberately loop-invariant in regs (128) + acc 64: needs the
// 256-reg budget that launch_bounds(256,1) granted in r2 (VGPR_Count=256, ok).
__global__ __launch_bounds__(256, 1) void k_apply(
    const float* __restrict__ X, const f16* __restrict__ Gh, const f16* __restrict__ Gl,
    float* __restrict__ Out, int per_blk) {
  __shared__ __align__(16) f16 SX[NN], ST[NN];
  const int t = threadIdx.x, w = t >> 6, l = t & 63;
  f16x8 bgh[16], bgl[16];
  pre_bf_glb(Gh, bgh, w, l);
  pre_bf_glb(Gl, bgl, w, l);
  f32x4 acc[4][4];
  for (int m = 0; m < per_blk; ++m) {
    const size_t b = (size_t)blockIdx.x * per_blk + m;
    load_g2l(X + b * NN, SX, t, 256);
    __syncthreads();
    // acc = X*G^T -> store^T = G*X = T
    zero_acc<4>(acc); mm_pre2<4>(SX, bgh, bgl, acc, w, l); __syncthreads();
    wb_t<4>(ST, acc, w, l, 1.f, 0.f); __syncthreads();
    // acc = T*G^T = G X G^T -> global (symmetric: transposed float4 store exact)
    zero_acc<4>(acc); mm_pre2<4>(ST, bgh, bgl, acc, w, l);
    float* O = Out + b * NN;
    const int tr0 = (w >> 1) * 64, tc0 = (w & 1) * 64;
    #pragma unroll
    for (int i = 0; i < 4; ++i) {
      const int rowb = tr0 + i*16 + ((l >> 4) << 2);
      #pragma unroll
      for (int j = 0; j < 4; ++j) {
        const int colg = tc0 + j*16 + (l & 15);
        *(f32x4*)(O + colg * 128 + rowb) = acc[i][j];
      }
    }
    __syncthreads();
  }
}

// =================== host ===================
extern "C" void kernel_launch(void* const* d_in, const int* in_sizes, int n_in,
                              void* d_out, int out_size, void* d_ws, size_t ws_size,
                              hipStream_t stream) {
  const float* X    = (const float*)d_in[0];
  const float* mean = (const float*)d_in[1];
  // d_in[2] (running_mean) mathematically unused: eta=1.0 makes
  // rm_sqrt @ powm(rm_invsqrt@BM@rm_invsqrt, 1) @ rm_sqrt == BM for ANY SPD rm.
  const int Bn = in_sizes[0] / NN;       // 2048

  float* wsf = (float*)d_ws;
  float* M0 = wsf;
  float* P  = wsf + NN;
  f16* hbase = (f16*)(wsf + 2 * (size_t)NN);
  f16 *Cph = hbase,            *Cpl = hbase + NN;
  f16 *Rh  = hbase + 2 * NN,   *Rl  = hbase + 3 * NN;
  f16 *Gh  = hbase + 4 * NN,   *Gl  = hbase + 5 * NN;
  float* Ppart = wsf + 5 * (size_t)NN;   // 256 slots (16 MB); also mean partials

  k_mean_part<<<dim3(16, 16), 256, 0, stream>>>(X, Ppart, Bn / 16);
  k_mean_fin<<<16, 256, 0, stream>>>(Ppart, M0, 1.f / (float)Bn);
  kB<<<1, 512, 0, stream>>>(M0, Cph, Cpl, Rh, Rl);
  k_batch_log<<<256, 512, 0, stream>>>(X, Cph, Cpl, Ppart, Bn / 256);
  k_reduceP<<<16, 256, 0, stream>>>(Ppart, P, 1.f / (float)Bn);
  kD<<<1, 512, 0, stream>>>(P, mean, Rh, Rl, Gh, Gl);
  k_apply<<<512, 256, 0, stream>>>(X, Gh, Gl, (float*)d_out, Bn / 512);
}

// Round 9
// 313.875 us; speedup vs baseline: 1.6042x; 1.1614x over previous
//
#include <hip/hip_runtime.h>

typedef _Float16 f16;
typedef _Float16 f16x8 __attribute__((ext_vector_type(8)));
typedef _Float16 f16x4 __attribute__((ext_vector_type(4)));
typedef float    f32x4 __attribute__((ext_vector_type(4)));

#define NN 16384   // 128*128

// ---- Chebyshev deg-13 approx of log(x) on x in [0.3, 3.5] -----------------
// x = m + h t, m=1.9 h=1.6 (SAME window as the passing Taylor rounds — r8's
// NaN was a window mismatch: coefficients for [0.185,2.02] with unscaled Cp
// put t up to 2.4, U^12 ~ 3.7e4 > f16 max).  c=h/m=0.8421, rho=0.5471,
// alpha_k = 2(-1)^{k+1} rho^k / k, truncation <= 7e-5 uniform.  Monomial
// coefficients verified at t=0,+-1,0.5,-0.75 vs ln(m+ht): residual <= 1.2e-4.
#define CHM 1.9f
#define CHH 1.6f
__device__ __constant__ float CB[14] = {
   0.6418302f,  0.8422835f, -0.3523330f,  0.1927408f,   // g0: b0..b3
  -0.1587888f,  0.1475312f,  0.1189440f, -0.2249536f,   // g1: b4..b7
  -0.4700032f,  0.5836800f,  0.4901376f, -0.5607424f,   // g2: b8..b11
  -0.2453504f,  0.2477460f };                           // g3: b12,b13

// ---------------- swizzled LDS index for 128x128 f16 (G4 XOR pattern) -------
__device__ __forceinline__ int swz(int r, int c) {
  return (r << 7) + ((((c >> 3) ^ (r & 7)) << 3) | (c & 7));
}

// load 128x128 fp32 (global) -> f16 swizzled LDS
__device__ __forceinline__ void load_g2l(const float* __restrict__ G, f16* buf, int t, int nt) {
  for (int ch = t; ch < 2048; ch += nt) {
    int r = ch >> 4, c8 = (ch & 15) << 3;
    const float* g = G + (r << 7) + c8;
    float4 v0 = *(const float4*)g;
    float4 v1 = *(const float4*)(g + 4);
    f16x8 h;
    h[0]=(f16)v0.x; h[1]=(f16)v0.y; h[2]=(f16)v0.z; h[3]=(f16)v0.w;
    h[4]=(f16)v1.x; h[5]=(f16)v1.y; h[6]=(f16)v1.z; h[7]=(f16)v1.w;
    *(f16x8*)(buf + swz(r, c8)) = h;
  }
}
// rows 64..127 only (second half; first half comes from the S4 prefetch)
__device__ __forceinline__ void load_g2l_rows64(const float* __restrict__ G, f16* buf, int t) {
  for (int ch = 1024 + t; ch < 2048; ch += 512) {
    int r = ch >> 4, c8 = (ch & 15) << 3;
    const float* g = G + (r << 7) + c8;
    float4 v0 = *(const float4*)g;
    float4 v1 = *(const float4*)(g + 4);
    f16x8 h;
    h[0]=(f16)v0.x; h[1]=(f16)v0.y; h[2]=(f16)v0.z; h[3]=(f16)v0.w;
    h[4]=(f16)v1.x; h[5]=(f16)v1.y; h[6]=(f16)v1.z; h[7]=(f16)v1.w;
    *(f16x8*)(buf + swz(r, c8)) = h;
  }
}
// load 128x128 f16 (global, row-major) -> swizzled LDS
__device__ __forceinline__ void load_g2l_h(const f16* __restrict__ G, f16* buf, int t, int nt) {
  for (int ch = t; ch < 2048; ch += nt) {
    int r = ch >> 4, c8 = (ch & 15) << 3;
    *(f16x8*)(buf + swz(r, c8)) = *(const f16x8*)(G + (r << 7) + c8);
  }
}
// async prefetch: raw fp32 rows 0..63 of next X (32KB = 2048 x 16B chunks)
// -> S4 (linear).  8 waves x 4 issues x 64 lanes x 16B = 32KB exactly.
__device__ __forceinline__ void stage_half(const float* __restrict__ Xn, f16* s4, int t) {
  const int w = t >> 6, l = t & 63;
  #pragma unroll
  for (int q = 0; q < 4; ++q) {
    const int cb = (w * 4 + q) * 64;           // wave-uniform 16B-chunk base
    const float* src = Xn + (size_t)(cb + l) * 4;
    __builtin_amdgcn_global_load_lds(
        (const __attribute__((address_space(1))) unsigned int*)src,
        (__attribute__((address_space(3))) unsigned int*)((char*)s4 + (size_t)cb * 16), 16, 0, 0);
  }
}
// staged raw fp32 (S4) -> swizzled f16 rows 0..63 of dst
__device__ __forceinline__ void convert_half(const f16* s4, f16* dst, int t) {
  for (int g = t; g < 1024; g += 512) {
    int r = g >> 4, c8 = (g & 15) << 3;
    const float* src = (const float*)s4 + g * 8;
    float4 v0 = *(const float4*)src;
    float4 v1 = *(const float4*)(src + 4);
    f16x8 h;
    h[0]=(f16)v0.x; h[1]=(f16)v0.y; h[2]=(f16)v0.z; h[3]=(f16)v0.w;
    h[4]=(f16)v1.x; h[5]=(f16)v1.y; h[6]=(f16)v1.z; h[7]=(f16)v1.w;
    *(f16x8*)(dst + swz(r, c8)) = h;
  }
}

template<int NI>
__device__ __forceinline__ void zero_acc(f32x4 (&acc)[NI][4]) {
  #pragma unroll
  for (int i = 0; i < NI; ++i)
    #pragma unroll
    for (int j = 0; j < 4; ++j) acc[i][j] = (f32x4){0.f, 0.f, 0.f, 0.f};
}

// acc += A * B̂^T, both from swizzled LDS (valid as A*B when B̂ symmetric)
template<int NI>
__device__ __forceinline__ void mm_lds(const f16* A, const f16* Bh,
                                       f32x4 (&acc)[NI][4], int w, int l) {
  const int tr0 = (w >> 1) * (16 * NI), tc0 = (w & 1) * 64;
  #pragma unroll
  for (int ks = 0; ks < 4; ++ks) {
    const int kb = ks * 32 + ((l >> 4) << 3);
    f16x8 af[NI], bf[4];
    #pragma unroll
    for (int i = 0; i < NI; ++i) af[i] = *(const f16x8*)(A  + swz(tr0 + i*16 + (l & 15), kb));
    #pragma unroll
    for (int j = 0; j < 4; ++j) bf[j] = *(const f16x8*)(Bh + swz(tc0 + j*16 + (l & 15), kb));
    #pragma unroll
    for (int i = 0; i < NI; ++i)
      #pragma unroll
      for (int j = 0; j < 4; ++j)
        acc[i][j] = __builtin_amdgcn_mfma_f32_16x16x32_f16(af[i], bf[j], acc[i][j], 0, 0, 0);
  }
}

// acc += A*(B1̂^T + B2̂^T), all from LDS, A-fragments read once (split-B hi+lo)
template<int NI>
__device__ __forceinline__ void mm_lds2b(const f16* A, const f16* B1, const f16* B2,
                                         f32x4 (&acc)[NI][4], int w, int l) {
  const int tr0 = (w >> 1) * (16 * NI), tc0 = (w & 1) * 64;
  #pragma unroll
  for (int ks = 0; ks < 4; ++ks) {
    const int kb = ks * 32 + ((l >> 4) << 3);
    f16x8 af[NI], b1[4], b2[4];
    #pragma unroll
    for (int i = 0; i < NI; ++i) af[i] = *(const f16x8*)(A  + swz(tr0 + i*16 + (l & 15), kb));
    #pragma unroll
    for (int j = 0; j < 4; ++j) {
      b1[j] = *(const f16x8*)(B1 + swz(tc0 + j*16 + (l & 15), kb));
      b2[j] = *(const f16x8*)(B2 + swz(tc0 + j*16 + (l & 15), kb));
    }
    #pragma unroll
    for (int i = 0; i < NI; ++i)
      #pragma unroll
      for (int j = 0; j < 4; ++j) {
        acc[i][j] = __builtin_amdgcn_mfma_f32_16x16x32_f16(af[i], b1[j], acc[i][j], 0, 0, 0);
        acc[i][j] = __builtin_amdgcn_mfma_f32_16x16x32_f16(af[i], b2[j], acc[i][j], 0, 0, 0);
      }
  }
}

// acc += A*(B1̂^T) + A*(B2̂^T), B̂ fragments preloaded in regs (k_apply only)
template<int NI>
__device__ __forceinline__ void mm_pre2(const f16* A, const f16x8* b1, const f16x8* b2,
                                        f32x4 (&acc)[NI][4], int w, int l) {
  const int tr0 = (w >> 1) * (16 * NI);
  #pragma unroll
  for (int ks = 0; ks < 4; ++ks) {
    const int kb = ks * 32 + ((l >> 4) << 3);
    f16x8 af[NI];
    #pragma unroll
    for (int i = 0; i < NI; ++i) af[i] = *(const f16x8*)(A + swz(tr0 + i*16 + (l & 15), kb));
    #pragma unroll
    for (int i = 0; i < NI; ++i)
      #pragma unroll
      for (int j = 0; j < 4; ++j) {
        acc[i][j] = __builtin_amdgcn_mfma_f32_16x16x32_f16(af[i], b1[ks*4+j], acc[i][j], 0, 0, 0);
        acc[i][j] = __builtin_amdgcn_mfma_f32_16x16x32_f16(af[i], b2[ks*4+j], acc[i][j], 0, 0, 0);
      }
  }
}
// preload B̂ fragments from row-major GLOBAL f16 (k_apply)
__device__ __forceinline__ void pre_bf_glb(const f16* __restrict__ B, f16x8* bfr, int w, int l) {
  const int tc0 = (w & 1) * 64;
  #pragma unroll
  for (int ks = 0; ks < 4; ++ks) {
    const int kb = ks * 32 + ((l >> 4) << 3);
    #pragma unroll
    for (int j = 0; j < 4; ++j)
      bfr[ks*4+j] = *(const f16x8*)(B + (tc0 + j*16 + (l & 15)) * 128 + kb);
  }
}
// preload output-position b64 chunks (transposed convention)
template<int NI>
__device__ __forceinline__ void pre_chunks(const f16* M, f16x4* Cc, int w, int l) {
  const int tr0 = (w >> 1) * (16 * NI), tc0 = (w & 1) * 64;
  #pragma unroll
  for (int i = 0; i < NI; ++i) {
    const int rowb = tr0 + i*16 + ((l >> 4) << 2);
    #pragma unroll
    for (int j = 0; j < 4; ++j)
      Cc[i*4+j] = *(const f16x4*)(M + swz(tc0 + j*16 + (l & 15), rowb));
  }
}

// transpose-packed writeback: buf[swz(col,row)] = alpha*acc + beta*[row==col]
template<int NI>
__device__ __forceinline__ void wb_t(f16* buf, const f32x4 (&acc)[NI][4], int w, int l,
                                     float alpha, float beta) {
  const int tr0 = (w >> 1) * (16 * NI), tc0 = (w & 1) * 64;
  #pragma unroll
  for (int i = 0; i < NI; ++i) {
    const int rowb = tr0 + i*16 + ((l >> 4) << 2);
    #pragma unroll
    for (int j = 0; j < 4; ++j) {
      const int colg = tc0 + j*16 + (l & 15);
      f16x4 h;
      #pragma unroll
      for (int r = 0; r < 4; ++r) {
        float v = alpha * acc[i][j][r];
        if (rowb + r == colg) v += beta;
        h[r] = (f16)v;
      }
      *(f16x4*)(buf + swz(colg, rowb)) = h;
    }
  }
}

// transpose-packed split writeback (hi+lo f16)
template<int NI>
__device__ __forceinline__ void wb_t_split(f16* bh, f16* bl, const f32x4 (&acc)[NI][4],
                                           int w, int l) {
  const int tr0 = (w >> 1) * (16 * NI), tc0 = (w & 1) * 64;
  #pragma unroll
  for (int i = 0; i < NI; ++i) {
    const int rowb = tr0 + i*16 + ((l >> 4) << 2);
    #pragma unroll
    for (int j = 0; j < 4; ++j) {
      const int colg = tc0 + j*16 + (l & 15);
      f16x4 hh, hl;
      #pragma unroll
      for (int r = 0; r < 4; ++r) {
        float v = acc[i][j][r];
        f16 hi = (f16)v;
        hh[r] = hi; hl[r] = (f16)(v - (float)hi);
      }
      *(f16x4*)(bh + swz(colg, rowb)) = hh;
      *(f16x4*)(bl + swz(colg, rowb)) = hl;
    }
  }
}

// transpose writeback: v = acc + d0*I + d1*Uc(reg) + d2*U2c(reg) + d3*U3(LDS C3)
template<int NI>
__device__ __forceinline__ void wb_t_combo3L(f16* buf, const f32x4 (&acc)[NI][4],
                                             const f16x4* Uc, const f16x4* U2c, const f16* C3,
                                             int w, int l, float d0, float d1, float d2, float d3) {
  const int tr0 = (w >> 1) * (16 * NI), tc0 = (w & 1) * 64;
  #pragma unroll
  for (int i = 0; i < NI; ++i) {
    const int rowb = tr0 + i*16 + ((l >> 4) << 2);
    #pragma unroll
    for (int j = 0; j < 4; ++j) {
      const int colg = tc0 + j*16 + (l & 15);
      f16x4 c3 = *(const f16x4*)(C3 + swz(colg, rowb));
      f16x4 h;
      #pragma unroll
      for (int r = 0; r < 4; ++r) {
        float v = acc[i][j][r] + d1 * (float)Uc[i*4+j][r] + d2 * (float)U2c[i*4+j][r]
                               + d3 * (float)c3[r];
        if (rowb + r == colg) v += d0;
        h[r] = (f16)v;
      }
      *(f16x4*)(buf + swz(colg, rowb)) = h;
    }
  }
}

// transpose writeback with combo read from LDS buffers C1,C2 (kD)
template<int NI>
__device__ __forceinline__ void wb_t_gc(f16* buf, const f32x4 (&acc)[NI][4],
                                        const f16* C1, const f16* C2,
                                        int w, int l, float d0, float d1, float d2) {
  const int tr0 = (w >> 1) * (16 * NI), tc0 = (w & 1) * 64;
  #pragma unroll
  for (int i = 0; i < NI; ++i) {
    const int rowb = tr0 + i*16 + ((l >> 4) << 2);
    #pragma unroll
    for (int j = 0; j < 4; ++j) {
      const int colg = tc0 + j*16 + (l & 15);
      f16x4 c1 = *(const f16x4*)(C1 + swz(colg, rowb));
      f16x4 c2 = *(const f16x4*)(C2 + swz(colg, rowb));
      f16x4 h;
      #pragma unroll
      for (int r = 0; r < 4; ++r) {
        float v = acc[i][j][r] + d1 * (float)c1[r] + d2 * (float)c2[r];
        if (rowb + r == colg) v += d0;
        h[r] = (f16)v;
      }
      *(f16x4*)(buf + swz(colg, rowb)) = h;
    }
  }
}

// =================== phase A: batch mean (float4) ===================
__global__ void k_mean_part(const float* __restrict__ X, float* __restrict__ part, int nper) {
  int e4 = blockIdx.x * 256 + threadIdx.x;     // grid (16,16): 4096 float4/matrix
  int bc = blockIdx.y;
  const float4* p = (const float4*)X + (size_t)bc * nper * 4096 + e4;
  float4 s = {0.f, 0.f, 0.f, 0.f};
  for (int b = 0; b < nper; ++b) {
    float4 v = p[(size_t)b * 4096];
    s.x += v.x; s.y += v.y; s.z += v.z; s.w += v.w;
  }
  ((float4*)part)[(size_t)bc * 4096 + e4] = s;
}
__global__ void k_mean_fin(const float* __restrict__ part, float* __restrict__ M0, float scale) {
  int e4 = blockIdx.x * 256 + threadIdx.x;     // 16 blocks
  float4 s = {0.f, 0.f, 0.f, 0.f};
  for (int c = 0; c < 16; ++c) {
    float4 v = ((const float4*)part)[(size_t)c * 4096 + e4];
    s.x += v.x; s.y += v.y; s.z += v.z; s.w += v.w;
  }
  s.x *= scale; s.y *= scale; s.z *= scale; s.w *= scale;
  ((float4*)M0)[e4] = s;
}

// =================== kB: Cp=M0^{-1/2} (split), R=M0^{1/2} (split) ===========
__global__ __launch_bounds__(512) void kB(
    const float* __restrict__ M0,
    f16* __restrict__ Cph, f16* __restrict__ Cpl,
    f16* __restrict__ Rh,  f16* __restrict__ Rl) {
  __shared__ __align__(16) f16 A1[NN], A2[NN], A3[NN], A4[NN];
  __shared__ float red[128];
  __shared__ float sS;
  const int t = threadIdx.x, w = t >> 6, l = t & 63;
  if (t < 128) red[t] = M0[t * 129];
  __syncthreads();
  for (int s = 64; s > 0; s >>= 1) { if (t < s) red[t] += red[t + s]; __syncthreads(); }
  if (t == 0) sS = red[0] / 128.f;
  __syncthreads();
  const float s = sS, inv = 1.f / s;
  for (int e = t; e < NN; e += 512) {
    int r = e >> 7, c = e & 127;
    A1[swz(r, c)] = (f16)(M0[e] * inv - (r == c ? 1.f : 0.f));
  }
  __syncthreads();
  f32x4 acc[2][4];
  zero_acc<2>(acc); mm_lds<2>(A1, A1, acc, w, l); wb_t<2>(A2, acc, w, l, 1.f, 0.f); __syncthreads();
  zero_acc<2>(acc); mm_lds<2>(A2, A1, acc, w, l); wb_t<2>(A3, acc, w, l, 1.f, 0.f); __syncthreads();
  zero_acc<2>(acc); mm_lds<2>(A2, A2, acc, w, l); wb_t<2>(A4, acc, w, l, 1.f, 0.f); __syncthreads();
  const float rs = sqrtf(s), irs = 1.f / rs;
  for (int e = t; e < NN; e += 512) {
    int r = e >> 7, c = e & 127; int ix = swz(r, c);
    float a1 = (float)A1[ix], a2 = (float)A2[ix], a3 = (float)A3[ix], a4 = (float)A4[ix];
    float d = (r == c) ? 1.f : 0.f;
    float cp = (d - 0.5f*a1 + 0.375f*a2 - 0.3125f*a3 + 0.2734375f*a4) * irs;
    float rr = (d + 0.5f*a1 - 0.125f*a2 + 0.0625f*a3 - 0.0390625f*a4) * rs;
    f16 ch = (f16)cp; Cph[e] = ch; Cpl[e] = (f16)(cp - (float)ch);
    f16 rh = (f16)rr; Rh[e]  = rh; Rl[e]  = (f16)(rr - (float)rh);
  }
}

// ===== phase C: sum of matrix logs — Chebyshev deg-13 on [0.3,3.5], PS U^4.
// 8 matmul passes/matrix (was 12 Taylor-31): 2 B0 + 3 powers + 2 Horner + final.
// All operands from LDS (r3-r5 lesson: hoisted reg preloads -> spill).
__global__ __launch_bounds__(512) void k_batch_log(
    const float* __restrict__ X, const f16* __restrict__ Cph, const f16* __restrict__ Cpl,
    float* __restrict__ Ppart, int per_blk) {
  __shared__ __align__(16) f16 S0[NN], S1[NN], S2[NN], S3[NN], S4[NN];  // 160 KB
  const int t = threadIdx.x, w = t >> 6, l = t & 63;
  f32x4 lsum[2][4]; zero_acc<2>(lsum);
  f32x4 acc[2][4];
  for (int m = 0; m < per_blk; ++m) {
    const size_t b = (size_t)blockIdx.x * per_blk + m;
    if (m == 0) {
      load_g2l(X + b * NN, S0, t, 512);
    } else {
      asm volatile("s_waitcnt vmcnt(0)" ::: "memory");
      __syncthreads();                    // S4 prefetch visible everywhere
      convert_half(S4, S0, t);            // rows 0..63 from prefetch
      load_g2l_rows64(X + b * NN, S0, t); // rows 64..127 direct
    }
    load_g2l_h(Cph, S2, t, 512);          // Cp hi -> S2 (L2-resident)
    load_g2l_h(Cpl, S3, t, 512);          // Cp lo -> S3
    __syncthreads();
    // pass1: acc = X*Cp^T -> store^T = Cp*X = T -> S1
    zero_acc<2>(acc); mm_lds2b<2>(S0, S2, S3, acc, w, l);
    wb_t<2>(S1, acc, w, l, 1.f, 0.f); __syncthreads();
    // pass2: acc = T*Cp = B0 -> U = (B0 - m)/h -> S0
    zero_acc<2>(acc); mm_lds2b<2>(S1, S2, S3, acc, w, l);
    wb_t<2>(S0, acc, w, l, 1.f / CHH, -CHM / CHH); __syncthreads();
    // U2 -> S2 (Cp dead), U3 -> S3, V=U4 -> S1
    zero_acc<2>(acc); mm_lds<2>(S0, S0, acc, w, l); wb_t<2>(S2, acc, w, l, 1.f, 0.f); __syncthreads();
    zero_acc<2>(acc); mm_lds<2>(S2, S0, acc, w, l); wb_t<2>(S3, acc, w, l, 1.f, 0.f); __syncthreads();
    zero_acc<2>(acc); mm_lds<2>(S2, S2, acc, w, l); wb_t<2>(S1, acc, w, l, 1.f, 0.f); __syncthreads();
    // snapshot U,U2 combo chunks (buffers get recycled); U3 chunks stay in S3
    f16x4 Uc[8], U2c[8];
    pre_chunks<2>(S0, Uc, w, l);
    pre_chunks<2>(S2, U2c, w, l);
    __syncthreads();
    // H-init: g3 = b12 I + b13 U -> S0 (in place over U)
    for (int g = t; g < 2048; g += 512) {
      int e0 = g * 8;
      f16x8 u = *(const f16x8*)(S0 + e0);
      int r = e0 >> 7;
      int c0 = ((((e0 >> 3) & 15) ^ (r & 7)) << 3);
      f16x8 h;
      #pragma unroll
      for (int k = 0; k < 8; ++k) {
        float v = CB[13] * (float)u[k];
        if (r == c0 + k) v += CB[12];
        h[k] = (f16)v;
      }
      *(f16x8*)(S0 + e0) = h;
    }
    __syncthreads();
    // prefetch rows 0..63 of next X into S4 (raw fp32) while Horner runs
    if (m + 1 < per_blk) stage_half(X + (b + 1) * NN, S4, t);
    // Horner jj=2,1: H <- H*V + g_jj, ping-pong S0 <-> S2 (1 barrier/pass)
    f16* pc = S0; f16* pn = S2;
    #pragma unroll
    for (int jj = 2; jj >= 1; --jj) {
      zero_acc<2>(acc);
      mm_lds<2>(pc, S1, acc, w, l);
      wb_t_combo3L<2>(pn, acc, Uc, U2c, S3, w, l,
                      CB[4*jj], CB[4*jj+1], CB[4*jj+2], CB[4*jj+3]);
      __syncthreads();
      f16* tmp = pc; pc = pn; pn = tmp;
    }
    // final jj=0: log = H*V + g0, accumulate into lsum, no store
    zero_acc<2>(acc);
    mm_lds<2>(pc, S1, acc, w, l);
    {
      const int tr0 = (w >> 1) * 32, tc0 = (w & 1) * 64;
      #pragma unroll
      for (int i = 0; i < 2; ++i) {
        const int rowb = tr0 + i*16 + ((l >> 4) << 2);
        #pragma unroll
        for (int j = 0; j < 4; ++j) {
          const int colg = tc0 + j*16 + (l & 15);
          f16x4 c3 = *(const f16x4*)(S3 + swz(colg, rowb));
          #pragma unroll
          for (int r = 0; r < 4; ++r) {
            float v = acc[i][j][r] + CB[1] * (float)Uc[i*4+j][r]
                    + CB[2] * (float)U2c[i*4+j][r] + CB[3] * (float)c3[r];
            if (rowb + r == colg) v += CB[0];
            lsum[i][j][r] += v;
          }
        }
      }
    }
    __syncthreads();
  }
  // store partials (sum of logs symmetric -> transposed float4 store exact)
  float* pp = Ppart + (size_t)blockIdx.x * NN;
  const int tr0 = (w >> 1) * 32, tc0 = (w & 1) * 64;
  #pragma unroll
  for (int i = 0; i < 2; ++i) {
    const int rowb = tr0 + i*16 + ((l >> 4) << 2);
    #pragma unroll
    for (int j = 0; j < 4; ++j) {
      const int colg = tc0 + j*16 + (l & 15);
      *(f32x4*)(pp + colg * 128 + rowb) = lsum[i][j];
    }
  }
}

__global__ void k_reduceP(const float* __restrict__ Pp, float* __restrict__ P, float invBn) {
  int e4 = blockIdx.x * 256 + threadIdx.x;    // 16 blocks
  f32x4 s = {0.f, 0.f, 0.f, 0.f};
  for (int b = 0; b < 256; ++b) {
    f32x4 v = ((const f32x4*)Pp)[(size_t)b * 4096 + e4];
    s = s + v;
  }
  ((f32x4*)P)[e4] = s * invBn;
}

// ========= kD: E=exp(P) (deg-8), BM=R E R, S=BM^{-1/2}, T=mean^{1/2}, G=T*S ==
__global__ __launch_bounds__(512) void kD(
    const float* __restrict__ P, const float* __restrict__ mean,
    const f16* __restrict__ Rh, const f16* __restrict__ Rl,
    f16* __restrict__ Gh, f16* __restrict__ Gl) {
  __shared__ __align__(16) f16 B1[NN], B2[NN], B3[NN], B4[NN];
  __shared__ float red[128];
  __shared__ float sv;
  const int t = threadIdx.x, w = t >> 6, l = t & 63;
  f32x4 acc[2][4];
  // mu = tr(P)/128
  if (t < 128) red[t] = P[t * 129];
  __syncthreads();
  for (int s = 64; s > 0; s >>= 1) { if (t < s) red[t] += red[t + s]; __syncthreads(); }
  if (t == 0) sv = red[0] / 128.f;
  __syncthreads();
  const float mu = sv;
  // D -> B1
  for (int e = t; e < NN; e += 512) {
    int r = e >> 7, c = e & 127;
    B1[swz(r, c)] = (f16)(P[e] - (r == c ? mu : 0.f));
  }
  __syncthreads();
  // D2 -> B2, D3 -> B3
  zero_acc<2>(acc); mm_lds<2>(B1, B1, acc, w, l); wb_t<2>(B2, acc, w, l, 1.f, 0.f); __syncthreads();
  zero_acc<2>(acc); mm_lds<2>(B2, B1, acc, w, l); wb_t<2>(B3, acc, w, l, 1.f, 0.f); __syncthreads();
  // T = g2 = I/720 + D/5040 + D2/40320 -> B4
  for (int g = t; g < 2048; g += 512) {
    int e0 = g * 8;
    f16x8 d1 = *(const f16x8*)(B1 + e0);
    f16x8 d2 = *(const f16x8*)(B2 + e0);
    int r = e0 >> 7;
    int c0 = ((((e0 >> 3) & 15) ^ (r & 7)) << 3);
    f16x8 h;
    #pragma unroll
    for (int k = 0; k < 8; ++k) {
      float v = (1.f/5040.f) * (float)d1[k] + (1.f/40320.f) * (float)d2[k];
      if (r == c0 + k) v += (1.f/720.f);
      h[k] = (f16)v;
    }
    *(f16x8*)(B4 + e0) = h;
  }
  __syncthreads();
  // T <- D3*T + g1 (g1 = I/6 + D/24 + D2/120), in place B4 (needs mid barrier)
  zero_acc<2>(acc); mm_lds<2>(B3, B4, acc, w, l); __syncthreads();
  wb_t_gc<2>(B4, acc, B1, B2, w, l, 1.f/6.f, 1.f/24.f, 1.f/120.f);
  __syncthreads();
  // E = e^mu * (D3*T + I + D + D2/2): split -> Eh:B2, El:B3
  zero_acc<2>(acc); mm_lds<2>(B3, B4, acc, w, l); __syncthreads();
  {
    const float emu = expf(mu);
    const int tr0 = (w >> 1) * 32, tc0 = (w & 1) * 64;
    #pragma unroll
    for (int i = 0; i < 2; ++i) {
      const int rowb = tr0 + i*16 + ((l >> 4) << 2);
      #pragma unroll
      for (int j = 0; j < 4; ++j) {
        const int colg = tc0 + j*16 + (l & 15);
        f16x4 dc  = *(const f16x4*)(B1 + swz(colg, rowb));
        f16x4 d2c = *(const f16x4*)(B2 + swz(colg, rowb));
        f16x4 hh, hl;
        #pragma unroll
        for (int r = 0; r < 4; ++r) {
          float v = acc[i][j][r] + (float)dc[r] + 0.5f * (float)d2c[r];
          if (rowb + r == colg) v += 1.f;
          v *= emu;
          f16 hi = (f16)v; hh[r] = hi; hl[r] = (f16)(v - (float)hi);
        }
        *(f16x4*)(B2 + swz(colg, rowb)) = hh;
        *(f16x4*)(B3 + swz(colg, rowb)) = hl;
      }
    }
  }
  __syncthreads();
  // R into LDS
  load_g2l_h(Rh, B1, t, 512);
  load_g2l_h(Rl, B4, t, 512);
  __syncthreads();
  // T1 = E*R (buffer holds (E*R)^T): split -> B2,B3
  zero_acc<2>(acc);
  mm_lds<2>(B2, B1, acc, w, l);   // Eh*Rh
  mm_lds<2>(B2, B4, acc, w, l);   // Eh*Rl
  mm_lds<2>(B3, B1, acc, w, l);   // El*Rh
  __syncthreads();
  wb_t_split<2>(B2, B3, acc, w, l);
  __syncthreads();
  // BM = R*T1: A=R, B̂buf=(E*R)^T -> split B2,B3 (BM symmetric)
  zero_acc<2>(acc);
  mm_lds<2>(B1, B2, acc, w, l);   // Rh*T1h
  mm_lds<2>(B1, B3, acc, w, l);   // Rh*T1l
  mm_lds<2>(B4, B2, acc, w, l);   // Rl*T1h
  __syncthreads();
  wb_t_split<2>(B2, B3, acc, w, l);
  __syncthreads();
  // s2 = tr(BM)/128
  if (t < 128) red[t] = (float)B2[swz(t, t)] + (float)B3[swz(t, t)];
  __syncthreads();
  for (int s = 64; s > 0; s >>= 1) { if (t < s) red[t] += red[t + s]; __syncthreads(); }
  if (t == 0) sv = red[0] / 128.f;
  __syncthreads();
  const float s2 = sv, inv2 = 1.f / s2;
  // F = BM/s2 - I -> B1
  for (int e = t; e < NN; e += 512) {
    int r = e >> 7, c = e & 127; int ix = swz(r, c);
    B1[ix] = (f16)(((float)B2[ix] + (float)B3[ix]) * inv2 - (r == c ? 1.f : 0.f));
  }
  __syncthreads();
  // F2 -> B4, F3 -> B2, F4 -> B3
  zero_acc<2>(acc); mm_lds<2>(B1, B1, acc, w, l); wb_t<2>(B4, acc, w, l, 1.f, 0.f); __syncthreads();
  zero_acc<2>(acc); mm_lds<2>(B4, B1, acc, w, l); wb_t<2>(B2, acc, w, l, 1.f, 0.f); __syncthreads();
  zero_acc<2>(acc); mm_lds<2>(B4, B4, acc, w, l); wb_t<2>(B3, acc, w, l, 1.f, 0.f); __syncthreads();
  // S = (I - F/2 + 3F2/8 - 5F3/16 + 35F4/128)/sqrt(s2): split -> Sh:B1, Sl:B4
  {
    const float is2 = 1.f / sqrtf(s2);
    for (int e = t; e < NN; e += 512) {
      int r = e >> 7, c = e & 127; int ix = swz(r, c);
      float f1 = (float)B1[ix], f2 = (float)B4[ix], f3 = (float)B2[ix], f4 = (float)B3[ix];
      float d = (r == c) ? 1.f : 0.f;
      float vv = (d - 0.5f*f1 + 0.375f*f2 - 0.3125f*f3 + 0.2734375f*f4) * is2;
      f16 hi = (f16)vv;
      B1[ix] = hi; B4[ix] = (f16)(vv - (float)hi);
    }
  }
  __syncthreads();
  // T_sqrt = mean^{1/2}: s3 = tr(mean)/128, M -> B2, M2 -> B3
  if (t < 128) red[t] = mean[t * 129];
  __syncthreads();
  for (int s = 64; s > 0; s >>= 1) { if (t < s) red[t] += red[t + s]; __syncthreads(); }
  if (t == 0) sv = red[0] / 128.f;
  __syncthreads();
  const float s3 = sv, inv3 = 1.f / s3;
  for (int e = t; e < NN; e += 512) {
    int r = e >> 7, c = e & 127;
    B2[swz(r, c)] = (f16)(mean[e] * inv3 - (r == c ? 1.f : 0.f));
  }
  __syncthreads();
  zero_acc<2>(acc); mm_lds<2>(B2, B2, acc, w, l); __syncthreads();
  wb_t<2>(B3, acc, w, l, 1.f, 0.f); __syncthreads();
  {
    const float rs3 = sqrtf(s3);
    for (int e = t; e < NN; e += 512) {
      int r = e >> 7, c = e & 127; int ix = swz(r, c);
      float m1 = (float)B2[ix], m2 = (float)B3[ix];
      float d = (r == c) ? 1.f : 0.f;
      float vv = (d + 0.5f*m1 - 0.125f*m2) * rs3;
      f16 hi = (f16)vv;
      B2[ix] = hi; B3[ix] = (f16)(vv - (float)hi);
    }
  }
  __syncthreads();
  // G = T*S: acc = S*T (A=S: B1,B4; B̂=T: B2,B3), store transposed -> G (global)
  zero_acc<2>(acc);
  mm_lds<2>(B1, B2, acc, w, l);   // Sh*Th
  mm_lds<2>(B1, B3, acc, w, l);   // Sh*Tl
  mm_lds<2>(B4, B2, acc, w, l);   // Sl*Th
  {
    const int tr0 = (w >> 1) * 32, tc0 = (w & 1) * 64;
    #pragma unroll
    for (int i = 0; i < 2; ++i) {
      const int rowb = tr0 + i*16 + ((l >> 4) << 2);
      #pragma unroll
      for (int j = 0; j < 4; ++j) {
        const int colg = tc0 + j*16 + (l & 15);
        f16x4 hh, hl;
        #pragma unroll
        for (int r = 0; r < 4; ++r) {
          float v = acc[i][j][r];
          f16 hi = (f16)v; hh[r] = hi; hl[r] = (f16)(v - (float)hi);
        }
        *(f16x4*)(Gh + colg * 128 + rowb) = hh;
        *(f16x4*)(Gl + colg * 128 + rowb) = hl;
      }
    }
  }
}

// =================== phase E: Xn = G * X * G^T ===================
__global__ __launch_bounds__(256, 1) void k_apply(
    const float* __restrict__ X, const f16* __restrict__ Gh, const f16* __restrict__ Gl,
    float* __restrict__ Out, int per_blk) {
  __shared__ __align__(16) f16 SX[NN], ST[NN];
  const int t = threadIdx.x, w = t >> 6, l = t & 63;
  f16x8 bgh[16], bgl[16];
  pre_bf_glb(Gh, bgh, w, l);
  pre_bf_glb(Gl, bgl, w, l);
  f32x4 acc[4][4];
  for (int m = 0; m < per_blk; ++m) {
    const size_t b = (size_t)blockIdx.x * per_blk + m;
    load_g2l(X + b * NN, SX, t, 256);
    __syncthreads();
    // acc = X*G^T -> store^T = G*X = T
    zero_acc<4>(acc); mm_pre2<4>(SX, bgh, bgl, acc, w, l); __syncthreads();
    wb_t<4>(ST, acc, w, l, 1.f, 0.f); __syncthreads();
    // acc = T*G^T = G X G^T -> global (symmetric: transposed float4 store exact)
    zero_acc<4>(acc); mm_pre2<4>(ST, bgh, bgl, acc, w, l);
    float* O = Out + b * NN;
    const int tr0 = (w >> 1) * 64, tc0 = (w & 1) * 64;
    #pragma unroll
    for (int i = 0; i < 4; ++i) {
      const int rowb = tr0 + i*16 + ((l >> 4) << 2);
      #pragma unroll
      for (int j = 0; j < 4; ++j) {
        const int colg = tc0 + j*16 + (l & 15);
        *(f32x4*)(O + colg * 128 + rowb) = acc[i][j];
      }
    }
    __syncthreads();
  }
}

// =================== host ===================
extern "C" void kernel_launch(void* const* d_in, const int* in_sizes, int n_in,
                              void* d_out, int out_size, void* d_ws, size_t ws_size,
                              hipStream_t stream) {
  const float* X    = (const float*)d_in[0];
  const float* mean = (const float*)d_in[1];
  // d_in[2] (running_mean) mathematically unused: eta=1.0 makes
  // rm_sqrt @ powm(rm_invsqrt@BM@rm_invsqrt, 1) @ rm_sqrt == BM for ANY SPD rm.
  const int Bn = in_sizes[0] / NN;       // 2048

  float* wsf = (float*)d_ws;
  float* M0 = wsf;
  float* P  = wsf + NN;
  f16* hbase = (f16*)(wsf + 2 * (size_t)NN);
  f16 *Cph = hbase,            *Cpl = hbase + NN;
  f16 *Rh  = hbase + 2 * NN,   *Rl  = hbase + 3 * NN;
  f16 *Gh  = hbase + 4 * NN,   *Gl  = hbase + 5 * NN;
  float* Ppart = wsf + 5 * (size_t)NN;   // 256 slots (16 MB); also mean partials

  k_mean_part<<<dim3(16, 16), 256, 0, stream>>>(X, Ppart, Bn / 16);
  k_mean_fin<<<16, 256, 0, stream>>>(Ppart, M0, 1.f / (float)Bn);
  kB<<<1, 512, 0, stream>>>(M0, Cph, Cpl, Rh, Rl);
  k_batch_log<<<256, 512, 0, stream>>>(X, Cph, Cpl, Ppart, Bn / 256);
  k_reduceP<<<16, 256, 0, stream>>>(Ppart, P, 1.f / (float)Bn);
  kD<<<1, 512, 0, stream>>>(P, mean, Rh, Rl, Gh, Gl);
  k_apply<<<512, 256, 0, stream>>>(X, Gh, Gl, (float*)d_out, Bn / 512);
}

// Round 10
// 270.654 us; speedup vs baseline: 1.8604x; 1.1597x over previous
//
#include <hip/hip_runtime.h>

typedef _Float16 f16;
typedef _Float16 f16x8 __attribute__((ext_vector_type(8)));
typedef _Float16 f16x4 __attribute__((ext_vector_type(4)));
typedef float    f32x4 __attribute__((ext_vector_type(4)));

#define NN 16384   // 128*128

// ---- Chebyshev deg-13 approx of log(x) on x in [0.3, 3.5] (verified r9) ----
#define CHM 1.9f
#define CHH 1.6f
__device__ __constant__ float CB[14] = {
   0.6418302f,  0.8422835f, -0.3523330f,  0.1927408f,   // g0: b0..b3
  -0.1587888f,  0.1475312f,  0.1189440f, -0.2249536f,   // g1: b4..b7
  -0.4700032f,  0.5836800f,  0.4901376f, -0.5607424f,   // g2: b8..b11
  -0.2453504f,  0.2477460f };                           // g3: b12,b13

// ---------------- swizzled LDS index for 128x128 f16 (G4 XOR pattern) -------
__device__ __forceinline__ int swz(int r, int c) {
  return (r << 7) + ((((c >> 3) ^ (r & 7)) << 3) | (c & 7));
}

// load 128x128 f16 (global, row-major) -> swizzled LDS (kD only)
__device__ __forceinline__ void load_g2l_h(const f16* __restrict__ G, f16* buf, int t, int nt) {
  for (int ch = t; ch < 2048; ch += nt) {
    int r = ch >> 4, c8 = (ch & 15) << 3;
    *(f16x8*)(buf + swz(r, c8)) = *(const f16x8*)(G + (r << 7) + c8);
  }
}

// async stage of a PRE-SWIZZLED 32KB f16 matrix -> LDS (linear copy).
// 512 thr: 8 waves x 4 issues x 64 lanes x 16B = 32KB exactly.
__device__ __forceinline__ void stage32_512(const f16* __restrict__ src, f16* dst, int t) {
  const int w = t >> 6, l = t & 63;
  #pragma unroll
  for (int q = 0; q < 4; ++q) {
    const int cb = (w * 4 + q) * 64;           // wave-uniform 16B-chunk base
    __builtin_amdgcn_global_load_lds(
        (const __attribute__((address_space(1))) unsigned int*)(src + (size_t)(cb + l) * 8),
        (__attribute__((address_space(3))) unsigned int*)((char*)dst + (size_t)cb * 16), 16, 0, 0);
  }
}
// 256 thr variant: 4 waves x 8 issues
__device__ __forceinline__ void stage32_256(const f16* __restrict__ src, f16* dst, int t) {
  const int w = t >> 6, l = t & 63;
  #pragma unroll
  for (int q = 0; q < 8; ++q) {
    const int cb = (w * 8 + q) * 64;
    __builtin_amdgcn_global_load_lds(
        (const __attribute__((address_space(1))) unsigned int*)(src + (size_t)(cb + l) * 8),
        (__attribute__((address_space(3))) unsigned int*)((char*)dst + (size_t)cb * 16), 16, 0, 0);
  }
}

template<int NI>
__device__ __forceinline__ void zero_acc(f32x4 (&acc)[NI][4]) {
  #pragma unroll
  for (int i = 0; i < NI; ++i)
    #pragma unroll
    for (int j = 0; j < 4; ++j) acc[i][j] = (f32x4){0.f, 0.f, 0.f, 0.f};
}

// acc += A * B̂^T, both from swizzled LDS (valid as A*B when B̂ symmetric)
template<int NI>
__device__ __forceinline__ void mm_lds(const f16* A, const f16* Bh,
                                       f32x4 (&acc)[NI][4], int w, int l) {
  const int tr0 = (w >> 1) * (16 * NI), tc0 = (w & 1) * 64;
  #pragma unroll
  for (int ks = 0; ks < 4; ++ks) {
    const int kb = ks * 32 + ((l >> 4) << 3);
    f16x8 af[NI], bf[4];
    #pragma unroll
    for (int i = 0; i < NI; ++i) af[i] = *(const f16x8*)(A  + swz(tr0 + i*16 + (l & 15), kb));
    #pragma unroll
    for (int j = 0; j < 4; ++j) bf[j] = *(const f16x8*)(Bh + swz(tc0 + j*16 + (l & 15), kb));
    #pragma unroll
    for (int i = 0; i < NI; ++i)
      #pragma unroll
      for (int j = 0; j < 4; ++j)
        acc[i][j] = __builtin_amdgcn_mfma_f32_16x16x32_f16(af[i], bf[j], acc[i][j], 0, 0, 0);
  }
}

// acc += A * B̂^T with B̂ fragments preloaded (k_apply; regs fit its 256 budget)
template<int NI>
__device__ __forceinline__ void mm_pre(const f16* A, const f16x8* bfr,
                                       f32x4 (&acc)[NI][4], int w, int l) {
  const int tr0 = (w >> 1) * (16 * NI);
  #pragma unroll
  for (int ks = 0; ks < 4; ++ks) {
    const int kb = ks * 32 + ((l >> 4) << 3);
    f16x8 af[NI];
    #pragma unroll
    for (int i = 0; i < NI; ++i) af[i] = *(const f16x8*)(A + swz(tr0 + i*16 + (l & 15), kb));
    #pragma unroll
    for (int i = 0; i < NI; ++i)
      #pragma unroll
      for (int j = 0; j < 4; ++j)
        acc[i][j] = __builtin_amdgcn_mfma_f32_16x16x32_f16(af[i], bfr[ks*4+j], acc[i][j], 0, 0, 0);
  }
}
// preload B̂ fragments from swizzled-LAYOUT GLOBAL f16 (k_apply G)
__device__ __forceinline__ void pre_bf_gswz(const f16* __restrict__ B, f16x8* bfr, int w, int l) {
  const int tc0 = (w & 1) * 64;
  #pragma unroll
  for (int ks = 0; ks < 4; ++ks) {
    const int kb = ks * 32 + ((l >> 4) << 3);
    #pragma unroll
    for (int j = 0; j < 4; ++j)
      bfr[ks*4+j] = *(const f16x8*)(B + swz(tc0 + j*16 + (l & 15), kb));
  }
}
// preload output-position b64 chunks (transposed convention)
template<int NI>
__device__ __forceinline__ void pre_chunks(const f16* M, f16x4* Cc, int w, int l) {
  const int tr0 = (w >> 1) * (16 * NI), tc0 = (w & 1) * 64;
  #pragma unroll
  for (int i = 0; i < NI; ++i) {
    const int rowb = tr0 + i*16 + ((l >> 4) << 2);
    #pragma unroll
    for (int j = 0; j < 4; ++j)
      Cc[i*4+j] = *(const f16x4*)(M + swz(tc0 + j*16 + (l & 15), rowb));
  }
}

// transpose-packed writeback: buf[swz(col,row)] = alpha*acc + beta*[row==col]
template<int NI>
__device__ __forceinline__ void wb_t(f16* buf, const f32x4 (&acc)[NI][4], int w, int l,
                                     float alpha, float beta) {
  const int tr0 = (w >> 1) * (16 * NI), tc0 = (w & 1) * 64;
  #pragma unroll
  for (int i = 0; i < NI; ++i) {
    const int rowb = tr0 + i*16 + ((l >> 4) << 2);
    #pragma unroll
    for (int j = 0; j < 4; ++j) {
      const int colg = tc0 + j*16 + (l & 15);
      f16x4 h;
      #pragma unroll
      for (int r = 0; r < 4; ++r) {
        float v = alpha * acc[i][j][r];
        if (rowb + r == colg) v += beta;
        h[r] = (f16)v;
      }
      *(f16x4*)(buf + swz(colg, rowb)) = h;
    }
  }
}

// transpose-packed split writeback (hi+lo f16) — kD internal
template<int NI>
__device__ __forceinline__ void wb_t_split(f16* bh, f16* bl, const f32x4 (&acc)[NI][4],
                                           int w, int l) {
  const int tr0 = (w >> 1) * (16 * NI), tc0 = (w & 1) * 64;
  #pragma unroll
  for (int i = 0; i < NI; ++i) {
    const int rowb = tr0 + i*16 + ((l >> 4) << 2);
    #pragma unroll
    for (int j = 0; j < 4; ++j) {
      const int colg = tc0 + j*16 + (l & 15);
      f16x4 hh, hl;
      #pragma unroll
      for (int r = 0; r < 4; ++r) {
        float v = acc[i][j][r];
        f16 hi = (f16)v;
        hh[r] = hi; hl[r] = (f16)(v - (float)hi);
      }
      *(f16x4*)(bh + swz(colg, rowb)) = hh;
      *(f16x4*)(bl + swz(colg, rowb)) = hl;
    }
  }
}

// transpose writeback: v = acc + d0*I + d1*Uc(reg) + d2*U2c(reg) + d3*U3(LDS C3)
template<int NI>
__device__ __forceinline__ void wb_t_combo3L(f16* buf, const f32x4 (&acc)[NI][4],
                                             const f16x4* Uc, const f16x4* U2c, const f16* C3,
                                             int w, int l, float d0, float d1, float d2, float d3) {
  const int tr0 = (w >> 1) * (16 * NI), tc0 = (w & 1) * 64;
  #pragma unroll
  for (int i = 0; i < NI; ++i) {
    const int rowb = tr0 + i*16 + ((l >> 4) << 2);
    #pragma unroll
    for (int j = 0; j < 4; ++j) {
      const int colg = tc0 + j*16 + (l & 15);
      f16x4 c3 = *(const f16x4*)(C3 + swz(colg, rowb));
      f16x4 h;
      #pragma unroll
      for (int r = 0; r < 4; ++r) {
        float v = acc[i][j][r] + d1 * (float)Uc[i*4+j][r] + d2 * (float)U2c[i*4+j][r]
                               + d3 * (float)c3[r];
        if (rowb + r == colg) v += d0;
        h[r] = (f16)v;
      }
      *(f16x4*)(buf + swz(colg, rowb)) = h;
    }
  }
}

// transpose writeback with combo read from LDS buffers C1,C2 (kD)
template<int NI>
__device__ __forceinline__ void wb_t_gc(f16* buf, const f32x4 (&acc)[NI][4],
                                        const f16* C1, const f16* C2,
                                        int w, int l, float d0, float d1, float d2) {
  const int tr0 = (w >> 1) * (16 * NI), tc0 = (w & 1) * 64;
  #pragma unroll
  for (int i = 0; i < NI; ++i) {
    const int rowb = tr0 + i*16 + ((l >> 4) << 2);
    #pragma unroll
    for (int j = 0; j < 4; ++j) {
      const int colg = tc0 + j*16 + (l & 15);
      f16x4 c1 = *(const f16x4*)(C1 + swz(colg, rowb));
      f16x4 c2 = *(const f16x4*)(C2 + swz(colg, rowb));
      f16x4 h;
      #pragma unroll
      for (int r = 0; r < 4; ++r) {
        float v = acc[i][j][r] + d1 * (float)c1[r] + d2 * (float)c2[r];
        if (rowb + r == colg) v += d0;
        h[r] = (f16)v;
      }
      *(f16x4*)(buf + swz(colg, rowb)) = h;
    }
  }
}

// ========== phase A: batch mean + Xh (pre-swizzled f16 copy of X) ==========
// grid (8, 32), 256 thr: thread owns 8-elem chunk ch, iterates its 64-matrix
// slice: accumulates fp32 mean partials AND stores f16 X at swizzled offsets
// (so batch_log/apply can global_load_lds it with zero VALU).
__global__ void k_mean_part(const float* __restrict__ X, f16* __restrict__ Xh,
                            float* __restrict__ part, int nper) {
  const int ch = blockIdx.x * 256 + threadIdx.x;   // 0..2047
  const int bc = blockIdx.y;
  const int r = ch >> 4, c8 = (ch & 15) << 3;
  const int dsw = swz(r, c8);
  const float* p = X + (size_t)bc * nper * NN + (size_t)ch * 8;
  f16* xh = Xh + (size_t)bc * nper * NN + dsw;
  f32x4 s0 = {0.f,0.f,0.f,0.f}, s1 = {0.f,0.f,0.f,0.f};
  for (int b = 0; b < nper; ++b) {
    const float* g = p + (size_t)b * NN;
    f32x4 v0 = *(const f32x4*)g;
    f32x4 v1 = *(const f32x4*)(g + 4);
    s0 = s0 + v0; s1 = s1 + v1;
    f16x8 h;
    h[0]=(f16)v0[0]; h[1]=(f16)v0[1]; h[2]=(f16)v0[2]; h[3]=(f16)v0[3];
    h[4]=(f16)v1[0]; h[5]=(f16)v1[1]; h[6]=(f16)v1[2]; h[7]=(f16)v1[3];
    *(f16x8*)(xh + (size_t)b * NN) = h;
  }
  f32x4* pp = (f32x4*)(part + (size_t)bc * NN);
  pp[ch * 2]     = s0;
  pp[ch * 2 + 1] = s1;
}
__global__ void k_mean_fin(const float* __restrict__ part, float* __restrict__ M0, float scale) {
  int e4 = blockIdx.x * 256 + threadIdx.x;     // 16 blocks
  f32x4 s = {0.f,0.f,0.f,0.f};
  for (int c = 0; c < 32; ++c) s = s + ((const f32x4*)part)[(size_t)c * 4096 + e4];
  ((f32x4*)M0)[e4] = s * scale;
}

// ====== kB: Cps = M0^{-1/2} (single f16, SWIZZLED layout), R split =========
__global__ __launch_bounds__(512) void kB(
    const float* __restrict__ M0, f16* __restrict__ Cps,
    f16* __restrict__ Rh, f16* __restrict__ Rl) {
  __shared__ __align__(16) f16 A1[NN], A2[NN], A3[NN], A4[NN];
  __shared__ float red[128];
  __shared__ float sS;
  const int t = threadIdx.x, w = t >> 6, l = t & 63;
  if (t < 128) red[t] = M0[t * 129];
  __syncthreads();
  for (int s = 64; s > 0; s >>= 1) { if (t < s) red[t] += red[t + s]; __syncthreads(); }
  if (t == 0) sS = red[0] / 128.f;
  __syncthreads();
  const float s = sS, inv = 1.f / s;
  for (int e = t; e < NN; e += 512) {
    int r = e >> 7, c = e & 127;
    A1[swz(r, c)] = (f16)(M0[e] * inv - (r == c ? 1.f : 0.f));
  }
  __syncthreads();
  f32x4 acc[2][4];
  zero_acc<2>(acc); mm_lds<2>(A1, A1, acc, w, l); wb_t<2>(A2, acc, w, l, 1.f, 0.f); __syncthreads();
  zero_acc<2>(acc); mm_lds<2>(A2, A1, acc, w, l); wb_t<2>(A3, acc, w, l, 1.f, 0.f); __syncthreads();
  zero_acc<2>(acc); mm_lds<2>(A2, A2, acc, w, l); wb_t<2>(A4, acc, w, l, 1.f, 0.f); __syncthreads();
  const float rs = sqrtf(s), irs = 1.f / rs;
  for (int e = t; e < NN; e += 512) {
    int r = e >> 7, c = e & 127; int ix = swz(r, c);
    float a1 = (float)A1[ix], a2 = (float)A2[ix], a3 = (float)A3[ix], a4 = (float)A4[ix];
    float d = (r == c) ? 1.f : 0.f;
    float cp = (d - 0.5f*a1 + 0.375f*a2 - 0.3125f*a3 + 0.2734375f*a4) * irs;
    float rr = (d + 0.5f*a1 - 0.125f*a2 + 0.0625f*a3 - 0.0390625f*a4) * rs;
    Cps[ix] = (f16)cp;                       // swizzled-layout single f16
    f16 rh = (f16)rr; Rh[e] = rh; Rl[e] = (f16)(rr - (float)rh);
  }
}

// ===== phase C: sum of matrix logs — Chebyshev deg-13, PS U^4, single Cp.
// 8 MFMA-units/matrix: 2 B0 + 3 powers + 2 Horner + final.  X & Cp arrive
// pre-swizzled f16 via global_load_lds (zero staging VALU).
__global__ __launch_bounds__(512) void k_batch_log(
    const f16* __restrict__ Xh, const f16* __restrict__ Cps,
    float* __restrict__ Ppart, int per_blk) {
  __shared__ __align__(16) f16 S0[NN], S1[NN], S2[NN], S3[NN], S4[NN];  // 160 KB
  const int t = threadIdx.x, w = t >> 6, l = t & 63;
  f32x4 lsum[2][4]; zero_acc<2>(lsum);
  f32x4 acc[2][4];
  for (int m = 0; m < per_blk; ++m) {
    const size_t b = (size_t)blockIdx.x * per_blk + m;
    if (m == 0) stage32_512(Xh + b * NN, S0, t);   // first matrix: direct
    stage32_512(Cps, S2, t);                        // Cp (L2-hot) each matrix
    asm volatile("s_waitcnt vmcnt(0)" ::: "memory");
    __syncthreads();
    if (m > 0) {                                    // prefetched X: S4 -> S0
      for (int g = t; g < 2048; g += 512)
        *(f16x8*)(S0 + g * 8) = *(const f16x8*)(S4 + g * 8);
    }
    __syncthreads();
    // pass1: acc = X*Cp^T -> store^T = Cp*X = T -> S1
    zero_acc<2>(acc); mm_lds<2>(S0, S2, acc, w, l);
    wb_t<2>(S1, acc, w, l, 1.f, 0.f); __syncthreads();
    // pass2: acc = T*Cp = B0 -> U = (B0 - m)/h -> S0
    zero_acc<2>(acc); mm_lds<2>(S1, S2, acc, w, l);
    wb_t<2>(S0, acc, w, l, 1.f / CHH, -CHM / CHH); __syncthreads();
    // U2 -> S2 (Cp dead), U3 -> S3, V=U4 -> S1
    zero_acc<2>(acc); mm_lds<2>(S0, S0, acc, w, l); wb_t<2>(S2, acc, w, l, 1.f, 0.f); __syncthreads();
    zero_acc<2>(acc); mm_lds<2>(S2, S0, acc, w, l); wb_t<2>(S3, acc, w, l, 1.f, 0.f); __syncthreads();
    zero_acc<2>(acc); mm_lds<2>(S2, S2, acc, w, l); wb_t<2>(S1, acc, w, l, 1.f, 0.f); __syncthreads();
    // snapshot U,U2 combo chunks; U3 chunks stay in S3
    f16x4 Uc[8], U2c[8];
    pre_chunks<2>(S0, Uc, w, l);
    pre_chunks<2>(S2, U2c, w, l);
    __syncthreads();
    // H-init: g3 = b12 I + b13 U -> S0 (in place over U)
    for (int g = t; g < 2048; g += 512) {
      int e0 = g * 8;
      f16x8 u = *(const f16x8*)(S0 + e0);
      int r = e0 >> 7;
      int c0 = ((((e0 >> 3) & 15) ^ (r & 7)) << 3);
      f16x8 h;
      #pragma unroll
      for (int k = 0; k < 8; ++k) {
        float v = CB[13] * (float)u[k];
        if (r == c0 + k) v += CB[12];
        h[k] = (f16)v;
      }
      *(f16x8*)(S0 + e0) = h;
    }
    __syncthreads();
    // prefetch next pre-swizzled X into S4 while Horner runs
    if (m + 1 < per_blk) stage32_512(Xh + (b + 1) * NN, S4, t);
    // Horner jj=2,1: H <- H*V + g_jj, ping-pong S0 <-> S2
    f16* pc = S0; f16* pn = S2;
    #pragma unroll
    for (int jj = 2; jj >= 1; --jj) {
      zero_acc<2>(acc);
      mm_lds<2>(pc, S1, acc, w, l);
      wb_t_combo3L<2>(pn, acc, Uc, U2c, S3, w, l,
                      CB[4*jj], CB[4*jj+1], CB[4*jj+2], CB[4*jj+3]);
      __syncthreads();
      f16* tmp = pc; pc = pn; pn = tmp;
    }
    // final jj=0: log = H*V + g0, accumulate into lsum
    zero_acc<2>(acc);
    mm_lds<2>(pc, S1, acc, w, l);
    {
      const int tr0 = (w >> 1) * 32, tc0 = (w & 1) * 64;
      #pragma unroll
      for (int i = 0; i < 2; ++i) {
        const int rowb = tr0 + i*16 + ((l >> 4) << 2);
        #pragma unroll
        for (int j = 0; j < 4; ++j) {
          const int colg = tc0 + j*16 + (l & 15);
          f16x4 c3 = *(const f16x4*)(S3 + swz(colg, rowb));
          #pragma unroll
          for (int r = 0; r < 4; ++r) {
            float v = acc[i][j][r] + CB[1] * (float)Uc[i*4+j][r]
                    + CB[2] * (float)U2c[i*4+j][r] + CB[3] * (float)c3[r];
            if (rowb + r == colg) v += CB[0];
            lsum[i][j][r] += v;
          }
        }
      }
    }
    __syncthreads();
  }
  float* pp = Ppart + (size_t)blockIdx.x * NN;
  const int tr0 = (w >> 1) * 32, tc0 = (w & 1) * 64;
  #pragma unroll
  for (int i = 0; i < 2; ++i) {
    const int rowb = tr0 + i*16 + ((l >> 4) << 2);
    #pragma unroll
    for (int j = 0; j < 4; ++j) {
      const int colg = tc0 + j*16 + (l & 15);
      *(f32x4*)(pp + colg * 128 + rowb) = lsum[i][j];
    }
  }
}

__global__ void k_reduceP(const float* __restrict__ Pp, float* __restrict__ P, float invBn) {
  int e4 = blockIdx.x * 256 + threadIdx.x;    // 16 blocks
  f32x4 s = {0.f, 0.f, 0.f, 0.f};
  for (int b = 0; b < 256; ++b) s = s + ((const f32x4*)Pp)[(size_t)b * 4096 + e4];
  ((f32x4*)P)[e4] = s * invBn;
}

// ========= kD: E=exp(P), BM=R E R, S=BM^{-1/2}, T=mean^{1/2}, G=T*S =========
// G stored SINGLE f16 at swizzled offsets (k_apply stages it directly).
__global__ __launch_bounds__(512) void kD(
    const float* __restrict__ P, const float* __restrict__ mean,
    const f16* __restrict__ Rh, const f16* __restrict__ Rl,
    f16* __restrict__ Gs) {
  __shared__ __align__(16) f16 B1[NN], B2[NN], B3[NN], B4[NN];
  __shared__ float red[128];
  __shared__ float sv;
  const int t = threadIdx.x, w = t >> 6, l = t & 63;
  f32x4 acc[2][4];
  if (t < 128) red[t] = P[t * 129];
  __syncthreads();
  for (int s = 64; s > 0; s >>= 1) { if (t < s) red[t] += red[t + s]; __syncthreads(); }
  if (t == 0) sv = red[0] / 128.f;
  __syncthreads();
  const float mu = sv;
  for (int e = t; e < NN; e += 512) {
    int r = e >> 7, c = e & 127;
    B1[swz(r, c)] = (f16)(P[e] - (r == c ? mu : 0.f));
  }
  __syncthreads();
  zero_acc<2>(acc); mm_lds<2>(B1, B1, acc, w, l); wb_t<2>(B2, acc, w, l, 1.f, 0.f); __syncthreads();
  zero_acc<2>(acc); mm_lds<2>(B2, B1, acc, w, l); wb_t<2>(B3, acc, w, l, 1.f, 0.f); __syncthreads();
  for (int g = t; g < 2048; g += 512) {
    int e0 = g * 8;
    f16x8 d1 = *(const f16x8*)(B1 + e0);
    f16x8 d2 = *(const f16x8*)(B2 + e0);
    int r = e0 >> 7;
    int c0 = ((((e0 >> 3) & 15) ^ (r & 7)) << 3);
    f16x8 h;
    #pragma unroll
    for (int k = 0; k < 8; ++k) {
      float v = (1.f/5040.f) * (float)d1[k] + (1.f/40320.f) * (float)d2[k];
      if (r == c0 + k) v += (1.f/720.f);
      h[k] = (f16)v;
    }
    *(f16x8*)(B4 + e0) = h;
  }
  __syncthreads();
  zero_acc<2>(acc); mm_lds<2>(B3, B4, acc, w, l); __syncthreads();
  wb_t_gc<2>(B4, acc, B1, B2, w, l, 1.f/6.f, 1.f/24.f, 1.f/120.f);
  __syncthreads();
  zero_acc<2>(acc); mm_lds<2>(B3, B4, acc, w, l); __syncthreads();
  {
    const float emu = expf(mu);
    const int tr0 = (w >> 1) * 32, tc0 = (w & 1) * 64;
    #pragma unroll
    for (int i = 0; i < 2; ++i) {
      const int rowb = tr0 + i*16 + ((l >> 4) << 2);
      #pragma unroll
      for (int j = 0; j < 4; ++j) {
        const int colg = tc0 + j*16 + (l & 15);
        f16x4 dc  = *(const f16x4*)(B1 + swz(colg, rowb));
        f16x4 d2c = *(const f16x4*)(B2 + swz(colg, rowb));
        f16x4 hh, hl;
        #pragma unroll
        for (int r = 0; r < 4; ++r) {
          float v = acc[i][j][r] + (float)dc[r] + 0.5f * (float)d2c[r];
          if (rowb + r == colg) v += 1.f;
          v *= emu;
          f16 hi = (f16)v; hh[r] = hi; hl[r] = (f16)(v - (float)hi);
        }
        *(f16x4*)(B2 + swz(colg, rowb)) = hh;
        *(f16x4*)(B3 + swz(colg, rowb)) = hl;
      }
    }
  }
  __syncthreads();
  load_g2l_h(Rh, B1, t, 512);
  load_g2l_h(Rl, B4, t, 512);
  __syncthreads();
  zero_acc<2>(acc);
  mm_lds<2>(B2, B1, acc, w, l);
  mm_lds<2>(B2, B4, acc, w, l);
  mm_lds<2>(B3, B1, acc, w, l);
  __syncthreads();
  wb_t_split<2>(B2, B3, acc, w, l);
  __syncthreads();
  zero_acc<2>(acc);
  mm_lds<2>(B1, B2, acc, w, l);
  mm_lds<2>(B1, B3, acc, w, l);
  mm_lds<2>(B4, B2, acc, w, l);
  __syncthreads();
  wb_t_split<2>(B2, B3, acc, w, l);
  __syncthreads();
  if (t < 128) red[t] = (float)B2[swz(t, t)] + (float)B3[swz(t, t)];
  __syncthreads();
  for (int s = 64; s > 0; s >>= 1) { if (t < s) red[t] += red[t + s]; __syncthreads(); }
  if (t == 0) sv = red[0] / 128.f;
  __syncthreads();
  const float s2 = sv, inv2 = 1.f / s2;
  for (int e = t; e < NN; e += 512) {
    int r = e >> 7, c = e & 127; int ix = swz(r, c);
    B1[ix] = (f16)(((float)B2[ix] + (float)B3[ix]) * inv2 - (r == c ? 1.f : 0.f));
  }
  __syncthreads();
  zero_acc<2>(acc); mm_lds<2>(B1, B1, acc, w, l); wb_t<2>(B4, acc, w, l, 1.f, 0.f); __syncthreads();
  zero_acc<2>(acc); mm_lds<2>(B4, B1, acc, w, l); wb_t<2>(B2, acc, w, l, 1.f, 0.f); __syncthreads();
  zero_acc<2>(acc); mm_lds<2>(B4, B4, acc, w, l); wb_t<2>(B3, acc, w, l, 1.f, 0.f); __syncthreads();
  {
    const float is2 = 1.f / sqrtf(s2);
    for (int e = t; e < NN; e += 512) {
      int r = e >> 7, c = e & 127; int ix = swz(r, c);
      float f1 = (float)B1[ix], f2 = (float)B4[ix], f3 = (float)B2[ix], f4 = (float)B3[ix];
      float d = (r == c) ? 1.f : 0.f;
      float vv = (d - 0.5f*f1 + 0.375f*f2 - 0.3125f*f3 + 0.2734375f*f4) * is2;
      f16 hi = (f16)vv;
      B1[ix] = hi; B4[ix] = (f16)(vv - (float)hi);
    }
  }
  __syncthreads();
  if (t < 128) red[t] = mean[t * 129];
  __syncthreads();
  for (int s = 64; s > 0; s >>= 1) { if (t < s) red[t] += red[t + s]; __syncthreads(); }
  if (t == 0) sv = red[0] / 128.f;
  __syncthreads();
  const float s3 = sv, inv3 = 1.f / s3;
  for (int e = t; e < NN; e += 512) {
    int r = e >> 7, c = e & 127;
    B2[swz(r, c)] = (f16)(mean[e] * inv3 - (r == c ? 1.f : 0.f));
  }
  __syncthreads();
  zero_acc<2>(acc); mm_lds<2>(B2, B2, acc, w, l); __syncthreads();
  wb_t<2>(B3, acc, w, l, 1.f, 0.f); __syncthreads();
  {
    const float rs3 = sqrtf(s3);
    for (int e = t; e < NN; e += 512) {
      int r = e >> 7, c = e & 127; int ix = swz(r, c);
      float m1 = (float)B2[ix], m2 = (float)B3[ix];
      float d = (r == c) ? 1.f : 0.f;
      float vv = (d + 0.5f*m1 - 0.125f*m2) * rs3;
      f16 hi = (f16)vv;
      B2[ix] = hi; B3[ix] = (f16)(vv - (float)hi);
    }
  }
  __syncthreads();
  // G = T*S: acc = S*T (A=S: B1,B4; B̂=T: B2,B3); store G^T... = G at swizzled
  // global offsets so k_apply can global_load_lds it (single f16).
  zero_acc<2>(acc);
  mm_lds<2>(B1, B2, acc, w, l);
  mm_lds<2>(B1, B3, acc, w, l);
  mm_lds<2>(B4, B2, acc, w, l);
  {
    const int tr0 = (w >> 1) * 32, tc0 = (w & 1) * 64;
    #pragma unroll
    for (int i = 0; i < 2; ++i) {
      const int rowb = tr0 + i*16 + ((l >> 4) << 2);
      #pragma unroll
      for (int j = 0; j < 4; ++j) {
        const int colg = tc0 + j*16 + (l & 15);
        f16x4 h;
        #pragma unroll
        for (int r = 0; r < 4; ++r) h[r] = (f16)acc[i][j][r];
        *(f16x4*)(Gs + swz(colg, rowb)) = h;   // G stored swizzled
      }
    }
  }
}

// =================== phase E: Xn = G * X * G^T ===================
// G single f16 in regs (64 VGPR); X staged async (pre-swizzled Xh);
// 64KB LDS -> 2 blocks/CU for latency overlap.
__global__ __launch_bounds__(256, 1) void k_apply(
    const f16* __restrict__ Xh, const f16* __restrict__ Gs,
    float* __restrict__ Out, int per_blk) {
  __shared__ __align__(16) f16 SX[NN], ST[NN];
  const int t = threadIdx.x, w = t >> 6, l = t & 63;
  f16x8 bg[16];
  pre_bf_gswz(Gs, bg, w, l);
  f32x4 acc[4][4];
  for (int m = 0; m < per_blk; ++m) {
    const size_t b = (size_t)blockIdx.x * per_blk + m;
    stage32_256(Xh + b * NN, SX, t);
    asm volatile("s_waitcnt vmcnt(0)" ::: "memory");
    __syncthreads();
    // acc = X*G^T -> store^T = G*X = T
    zero_acc<4>(acc); mm_pre<4>(SX, bg, acc, w, l); __syncthreads();
    wb_t<4>(ST, acc, w, l, 1.f, 0.f); __syncthreads();
    // acc = T*G^T = G X G^T -> global (symmetric: transposed f32x4 store exact)
    zero_acc<4>(acc); mm_pre<4>(ST, bg, acc, w, l);
    float* O = Out + b * NN;
    const int tr0 = (w >> 1) * 64, tc0 = (w & 1) * 64;
    #pragma unroll
    for (int i = 0; i < 4; ++i) {
      const int rowb = tr0 + i*16 + ((l >> 4) << 2);
      #pragma unroll
      for (int j = 0; j < 4; ++j) {
        const int colg = tc0 + j*16 + (l & 15);
        *(f32x4*)(O + colg * 128 + rowb) = acc[i][j];
      }
    }
    __syncthreads();
  }
}

// =================== host ===================
extern "C" void kernel_launch(void* const* d_in, const int* in_sizes, int n_in,
                              void* d_out, int out_size, void* d_ws, size_t ws_size,
                              hipStream_t stream) {
  const float* X    = (const float*)d_in[0];
  const float* mean = (const float*)d_in[1];
  // d_in[2] (running_mean) mathematically unused: eta=1.0 makes
  // rm_sqrt @ powm(rm_invsqrt@BM@rm_invsqrt, 1) @ rm_sqrt == BM for ANY SPD rm.
  const int Bn = in_sizes[0] / NN;       // 2048

  float* wsf = (float*)d_ws;
  float* M0 = wsf;
  float* P  = wsf + NN;
  f16* hbase = (f16*)(wsf + 2 * (size_t)NN);
  f16 *Cps = hbase;                      // swizzled single-f16 Cp
  f16 *Rh  = hbase + NN, *Rl = hbase + 2 * NN;
  f16 *Gs  = hbase + 3 * NN;             // swizzled single-f16 G
  float* Ppart = wsf + 4 * (size_t)NN;   // 256 slots (16 MB); also mean partials
  f16* Xh = (f16*)(wsf + (4 + 256) * (size_t)NN);  // 64 MB pre-swizzled f16 X

  k_mean_part<<<dim3(8, 32), 256, 0, stream>>>(X, Xh, Ppart, Bn / 32);
  k_mean_fin<<<16, 256, 0, stream>>>(Ppart, M0, 1.f / (float)Bn);
  kB<<<1, 512, 0, stream>>>(M0, Cps, Rh, Rl);
  k_batch_log<<<256, 512, 0, stream>>>(Xh, Cps, Ppart, Bn / 256);
  k_reduceP<<<16, 256, 0, stream>>>(Ppart, P, 1.f / (float)Bn);
  kD<<<1, 512, 0, stream>>>(P, mean, Rh, Rl, Gs);
  k_apply<<<512, 256, 0, stream>>>(Xh, Gs, (float*)d_out, Bn / 512);
}